// Round 1
// baseline (1294.440 us; speedup 1.0000x reference)
//
#include <hip/hip_runtime.h>
#include <hip/hip_bf16.h>
#include <stdint.h>

#define N_NODES 50000
#define N_EDGES 800000
#define HID 128
#define NODE_IN 16
#define NODE_OUT 3

typedef __attribute__((ext_vector_type(8))) short short8;
typedef __attribute__((ext_vector_type(4))) float f32x4;

__device__ __forceinline__ unsigned short f2bf(float f) {
    union { float f; unsigned int u; } v; v.f = f;
    unsigned int u = v.u;
    u += 0x7fff + ((u >> 16) & 1);   // round-to-nearest-even
    return (unsigned short)(u >> 16);
}
__device__ __forceinline__ float bf2f(unsigned short s) {
    union { unsigned int u; float f; } v; v.u = ((unsigned int)s) << 16;
    return v.f;
}

// Pre-swizzle a [K,128] fp32 weight matrix into MFMA B-fragment order (bf16):
// dst[((kt*8+nt)*64 + lane)*8 + j] = W[kt*32 + (lane>>4)*8 + j][nt*16 + (lane&15)]
__global__ void swizzle_w(const float* __restrict__ src, unsigned short* __restrict__ dst, int K) {
    int d = blockIdx.x * 256 + threadIdx.x;
    if (d >= K * 128) return;
    int j = d & 7;
    int l = (d >> 3) & 63;
    int t = d >> 9;            // kt*8 + nt
    int nt = t & 7;
    int kt = t >> 3;
    int k = kt * 32 + ((l >> 4) << 3) + j;
    int n = (nt << 4) + (l & 15);
    dst[d] = f2bf(src[k * 128 + n]);
}

// h = x @ enc_w + enc_b   (bf16 output)
__global__ void encoder_kernel(const float* __restrict__ x, const float* __restrict__ enc_w,
                               const float* __restrict__ enc_b, unsigned short* __restrict__ h) {
    __shared__ float wts[NODE_IN * HID];
    __shared__ float bts[HID];
    __shared__ float xs[64][NODE_IN];
    int t = threadIdx.x;
    int n0 = blockIdx.x * 64;
    for (int i = t; i < NODE_IN * HID; i += 256) wts[i] = enc_w[i];
    if (t < HID) bts[t] = enc_b[t];
    for (int i = t; i < 64 * NODE_IN; i += 256) {
        int nl = i >> 4, ii = i & 15;
        int n = n0 + nl;
        xs[nl][ii] = (n < N_NODES) ? x[n * NODE_IN + ii] : 0.f;
    }
    __syncthreads();
    for (int o = t; o < 64 * HID; o += 256) {
        int nl = o >> 7, c = o & 127;
        int n = n0 + nl;
        if (n >= N_NODES) continue;
        float acc = bts[c];
        #pragma unroll
        for (int i = 0; i < NODE_IN; i++) acc += xs[nl][i] * wts[i * HID + c];
        h[n * HID + c] = f2bf(acc);
    }
}

// Edge MLP fused with scatter-add: agg[col[e]] += MLP(cat(h[row[e]], h[col[e]]))
__global__ __launch_bounds__(256, 2) void edge_kernel(
    const unsigned short* __restrict__ h, const int* __restrict__ rowp, const int* __restrict__ colp,
    const unsigned short* __restrict__ w1s, const float* __restrict__ b1,
    const unsigned short* __restrict__ w2s, const float* __restrict__ b2,
    float* __restrict__ agg)
{
    __shared__ unsigned short in_s[64][264];   // 64 edges x 256 feats, +8 pad
    __shared__ unsigned short hid_s[64][136];  // 64 edges x 128 hid, +8 pad
    __shared__ int row_s[64], col_s[64];
    int t = threadIdx.x;
    int wave = t >> 6, l = t & 63, q = l >> 4, l16 = l & 15;
    int e0 = blockIdx.x * 64;

    if (t < 64) row_s[t] = rowp[e0 + t];
    else if (t < 128) col_s[t - 64] = colp[e0 + t - 64];
    __syncthreads();

    // Gather: 64 edges x 2 halves x 16 chunks of 16B
    #pragma unroll
    for (int it = 0; it < 8; it++) {
        int g = it * 256 + t;
        int el = g >> 5, sub = g & 31, half = sub >> 4, li = sub & 15;
        int node = half ? col_s[el] : row_s[el];
        short8 v = *(const short8*)(h + node * HID + li * 8);
        *(short8*)&in_s[el][half * HID + li * 8] = v;
    }
    __syncthreads();

    // GEMM1: [16 edges/wave x 256] x [256 x 128] -> ReLU -> hid_s
    f32x4 acc[8];
    #pragma unroll
    for (int nt = 0; nt < 8; nt++) acc[nt] = (f32x4){0.f, 0.f, 0.f, 0.f};
    #pragma unroll
    for (int kt = 0; kt < 8; kt++) {
        short8 a = *(const short8*)&in_s[wave * 16 + l16][kt * 32 + q * 8];
        #pragma unroll
        for (int nt = 0; nt < 8; nt++) {
            short8 b = *(const short8*)(w1s + ((kt * 8 + nt) * 64 + l) * 8);
            acc[nt] = __builtin_amdgcn_mfma_f32_16x16x32_bf16(a, b, acc[nt], 0, 0, 0);
        }
    }
    #pragma unroll
    for (int nt = 0; nt < 8; nt++) {
        float bv = b1[nt * 16 + l16];
        #pragma unroll
        for (int r = 0; r < 4; r++) {
            float v = acc[nt][r] + bv;
            v = v > 0.f ? v : 0.f;
            hid_s[wave * 16 + q * 4 + r][nt * 16 + l16] = f2bf(v);
        }
    }
    __syncthreads();

    // GEMM2: [16 x 128] x [128 x 128] + bias -> atomic scatter to agg
    f32x4 acc2[8];
    #pragma unroll
    for (int nt = 0; nt < 8; nt++) acc2[nt] = (f32x4){0.f, 0.f, 0.f, 0.f};
    #pragma unroll
    for (int kt = 0; kt < 4; kt++) {
        short8 a = *(const short8*)&hid_s[wave * 16 + l16][kt * 32 + q * 8];
        #pragma unroll
        for (int nt = 0; nt < 8; nt++) {
            short8 b = *(const short8*)(w2s + ((kt * 8 + nt) * 64 + l) * 8);
            acc2[nt] = __builtin_amdgcn_mfma_f32_16x16x32_bf16(a, b, acc2[nt], 0, 0, 0);
        }
    }
    #pragma unroll
    for (int nt = 0; nt < 8; nt++) {
        float bv = b2[nt * 16 + l16];
        #pragma unroll
        for (int r = 0; r < 4; r++) {
            float v = acc2[nt][r] + bv;
            int m2 = wave * 16 + q * 4 + r;
            int d = col_s[m2];
            unsafeAtomicAdd(&agg[d * HID + nt * 16 + l16], v);
        }
    }
}

// Node MLP with residual: h += MLP(cat(h, agg))
__global__ __launch_bounds__(256, 2) void node_kernel(
    unsigned short* __restrict__ h, const float* __restrict__ agg,
    const unsigned short* __restrict__ w1s, const float* __restrict__ b1,
    const unsigned short* __restrict__ w2s, const float* __restrict__ b2)
{
    __shared__ unsigned short in_s[64][264];
    __shared__ unsigned short hid_s[64][136];
    int t = threadIdx.x;
    int wave = t >> 6, l = t & 63, q = l >> 4, l16 = l & 15;
    int n0 = blockIdx.x * 64;

    #pragma unroll
    for (int it = 0; it < 8; it++) {
        int g = it * 256 + t;
        int nl = g >> 5, sub = g & 31, half = sub >> 4, li = sub & 15;
        int n = n0 + nl;
        short8 v = (short8){0, 0, 0, 0, 0, 0, 0, 0};
        if (n < N_NODES) {
            if (half == 0) {
                v = *(const short8*)(h + n * HID + li * 8);
            } else {
                const float* ap = agg + n * HID + li * 8;
                #pragma unroll
                for (int j = 0; j < 8; j++) ((unsigned short*)&v)[j] = f2bf(ap[j]);
            }
        }
        *(short8*)&in_s[nl][half * HID + li * 8] = v;
    }
    __syncthreads();

    f32x4 acc[8];
    #pragma unroll
    for (int nt = 0; nt < 8; nt++) acc[nt] = (f32x4){0.f, 0.f, 0.f, 0.f};
    #pragma unroll
    for (int kt = 0; kt < 8; kt++) {
        short8 a = *(const short8*)&in_s[wave * 16 + l16][kt * 32 + q * 8];
        #pragma unroll
        for (int nt = 0; nt < 8; nt++) {
            short8 b = *(const short8*)(w1s + ((kt * 8 + nt) * 64 + l) * 8);
            acc[nt] = __builtin_amdgcn_mfma_f32_16x16x32_bf16(a, b, acc[nt], 0, 0, 0);
        }
    }
    #pragma unroll
    for (int nt = 0; nt < 8; nt++) {
        float bv = b1[nt * 16 + l16];
        #pragma unroll
        for (int r = 0; r < 4; r++) {
            float v = acc[nt][r] + bv;
            v = v > 0.f ? v : 0.f;
            hid_s[wave * 16 + q * 4 + r][nt * 16 + l16] = f2bf(v);
        }
    }
    __syncthreads();

    f32x4 acc2[8];
    #pragma unroll
    for (int nt = 0; nt < 8; nt++) acc2[nt] = (f32x4){0.f, 0.f, 0.f, 0.f};
    #pragma unroll
    for (int kt = 0; kt < 4; kt++) {
        short8 a = *(const short8*)&hid_s[wave * 16 + l16][kt * 32 + q * 8];
        #pragma unroll
        for (int nt = 0; nt < 8; nt++) {
            short8 b = *(const short8*)(w2s + ((kt * 8 + nt) * 64 + l) * 8);
            acc2[nt] = __builtin_amdgcn_mfma_f32_16x16x32_bf16(a, b, acc2[nt], 0, 0, 0);
        }
    }
    #pragma unroll
    for (int nt = 0; nt < 8; nt++) {
        float bv = b2[nt * 16 + l16];
        #pragma unroll
        for (int r = 0; r < 4; r++) {
            float v = acc2[nt][r] + bv;
            int m2 = wave * 16 + q * 4 + r;
            int n = n0 + m2;
            if (n < N_NODES) {
                int c = nt * 16 + l16;
                float hv = bf2f(in_s[m2][c]);   // old h (staged in half 0)
                h[n * HID + c] = f2bf(hv + v);  // residual
            }
        }
    }
}

// out = h @ dec_w + dec_b
__global__ void decoder_kernel(const unsigned short* __restrict__ h, const float* __restrict__ dec_w,
                               const float* __restrict__ dec_b, float* __restrict__ out) {
    __shared__ float dw[HID * NODE_OUT];
    __shared__ float db[NODE_OUT];
    int t = threadIdx.x;
    for (int i = t; i < HID * NODE_OUT; i += 256) dw[i] = dec_w[i];
    if (t < NODE_OUT) db[t] = dec_b[t];
    __syncthreads();
    int n = blockIdx.x * 256 + t;
    if (n >= N_NODES) return;
    float a0 = db[0], a1 = db[1], a2 = db[2];
    #pragma unroll 4
    for (int k8 = 0; k8 < 16; k8++) {
        short8 hv = *(const short8*)(h + n * HID + k8 * 8);
        #pragma unroll
        for (int j = 0; j < 8; j++) {
            float f = bf2f(((unsigned short*)&hv)[j]);
            int k = k8 * 8 + j;
            a0 += f * dw[k * 3 + 0];
            a1 += f * dw[k * 3 + 1];
            a2 += f * dw[k * 3 + 2];
        }
    }
    out[n * 3 + 0] = a0;
    out[n * 3 + 1] = a1;
    out[n * 3 + 2] = a2;
}

extern "C" void kernel_launch(void* const* d_in, const int* in_sizes, int n_in,
                              void* d_out, int out_size, void* d_ws, size_t ws_size,
                              hipStream_t stream) {
    const float* x       = (const float*)d_in[0];
    const int*   ei      = (const int*)d_in[1];
    const float* enc_w   = (const float*)d_in[2];
    const float* enc_b   = (const float*)d_in[3];
    const float* dec_w   = (const float*)d_in[4];
    const float* dec_b   = (const float*)d_in[5];
    const float* edge_w1 = (const float*)d_in[6];
    const float* edge_b1 = (const float*)d_in[7];
    const float* edge_w2 = (const float*)d_in[8];
    const float* edge_b2 = (const float*)d_in[9];
    const float* node_w1 = (const float*)d_in[10];
    const float* node_b1 = (const float*)d_in[11];
    const float* node_w2 = (const float*)d_in[12];
    const float* node_b2 = (const float*)d_in[13];

    char* ws = (char*)d_ws;
    unsigned short* h   = (unsigned short*)ws;               // 50000*128*2 = 12.8 MB
    float*          agg = (float*)(ws + 12800000);           // 50000*128*4 = 25.6 MB
    unsigned short* swz = (unsigned short*)(ws + 38400000);  // 294912*2 B swizzled weights

    const int* rowp = ei;            // edge_index[0] = source
    const int* colp = ei + N_EDGES;  // edge_index[1] = destination

    // Pre-swizzle all 12 weight matrices into B-fragment bf16 layout
    for (int L = 0; L < 3; L++) {
        unsigned short* base = swz + (size_t)L * 98304;
        swizzle_w<<<128, 256, 0, stream>>>(edge_w1 + (size_t)L * 256 * 128, base,         256);
        swizzle_w<<<64,  256, 0, stream>>>(edge_w2 + (size_t)L * 128 * 128, base + 32768, 128);
        swizzle_w<<<128, 256, 0, stream>>>(node_w1 + (size_t)L * 256 * 128, base + 49152, 256);
        swizzle_w<<<64,  256, 0, stream>>>(node_w2 + (size_t)L * 128 * 128, base + 81920, 128);
    }

    encoder_kernel<<<782, 256, 0, stream>>>(x, enc_w, enc_b, h);

    for (int L = 0; L < 3; L++) {
        unsigned short* base = swz + (size_t)L * 98304;
        hipMemsetAsync(agg, 0, (size_t)N_NODES * HID * 4, stream);
        edge_kernel<<<12500, 256, 0, stream>>>(h, rowp, colp,
                                               base,         edge_b1 + (size_t)L * HID,
                                               base + 32768, edge_b2 + (size_t)L * HID, agg);
        node_kernel<<<782, 256, 0, stream>>>(h, agg,
                                             base + 49152, node_b1 + (size_t)L * HID,
                                             base + 81920, node_b2 + (size_t)L * HID);
    }

    decoder_kernel<<<196, 256, 0, stream>>>(h, dec_w, dec_b, (float*)d_out);
}

// Round 2
// 947.085 us; speedup vs baseline: 1.3668x; 1.3668x over previous
//
#include <hip/hip_runtime.h>
#include <hip/hip_bf16.h>
#include <stdint.h>

#define N_NODES 50000
#define N_EDGES 800000
#define HID 128
#define NODE_IN 16
#define NODE_OUT 3

typedef __attribute__((ext_vector_type(8))) short short8;
typedef __attribute__((ext_vector_type(4))) float f32x4;

__device__ __forceinline__ unsigned short f2bf(float f) {
    union { float f; unsigned int u; } v; v.f = f;
    unsigned int u = v.u;
    u += 0x7fff + ((u >> 16) & 1);   // round-to-nearest-even
    return (unsigned short)(u >> 16);
}
__device__ __forceinline__ float bf2f(unsigned short s) {
    union { unsigned int u; float f; } v; v.u = ((unsigned int)s) << 16;
    return v.f;
}

// ---------------- counting sort of edges by destination ----------------

__global__ void hist_kernel(const int* __restrict__ colp, int* __restrict__ cnt) {
    int e = blockIdx.x * 256 + threadIdx.x;
    if (e < N_EDGES) atomicAdd(&cnt[colp[e]], 1);
}

// per-256-block exclusive scan + block sums
__global__ void scan1_kernel(const int* __restrict__ cnt, int* __restrict__ ex,
                             int* __restrict__ bsums) {
    __shared__ int s[256];
    int t = threadIdx.x, i = blockIdx.x * 256 + t;
    int v = (i < N_NODES) ? cnt[i] : 0;
    s[t] = v;
    __syncthreads();
    for (int off = 1; off < 256; off <<= 1) {
        int u = (t >= off) ? s[t - off] : 0;
        __syncthreads();
        s[t] += u;
        __syncthreads();
    }
    if (i < N_NODES) ex[i] = s[t] - v;
    if (t == 255) bsums[blockIdx.x] = s[255];
}

// exclusive scan of the 196 block sums (single block)
__global__ void scan2_kernel(int* bsums, int nblk) {
    __shared__ int s[256];
    int t = threadIdx.x;
    int v = (t < nblk) ? bsums[t] : 0;
    s[t] = v;
    __syncthreads();
    for (int off = 1; off < 256; off <<= 1) {
        int u = (t >= off) ? s[t - off] : 0;
        __syncthreads();
        s[t] += u;
        __syncthreads();
    }
    if (t < nblk) bsums[t] = s[t] - v;
}

__global__ void scan3_kernel(const int* __restrict__ ex, const int* __restrict__ bsums,
                             int* __restrict__ cursor) {
    int i = blockIdx.x * 256 + threadIdx.x;
    if (i < N_NODES) cursor[i] = ex[i] + bsums[i >> 8];
}

__global__ void scatter_kernel(const int* __restrict__ rowp, const int* __restrict__ colp,
                               int* __restrict__ cursor,
                               int* __restrict__ rows_sorted, int* __restrict__ cols_sorted) {
    int e = blockIdx.x * 256 + threadIdx.x;
    if (e >= N_EDGES) return;
    int r = rowp[e], c = colp[e];
    int pos = atomicAdd(&cursor[c], 1);
    rows_sorted[pos] = r;
    cols_sorted[pos] = c;
}

// ---------------- weight pre-swizzle into MFMA B-fragment order ----------------
// dst[((kt*8+nt)*64 + lane)*8 + j] = W[kt*32 + (lane>>4)*8 + j][nt*16 + (lane&15)]
__global__ void swizzle_w(const float* __restrict__ src, unsigned short* __restrict__ dst, int K) {
    int d = blockIdx.x * 256 + threadIdx.x;
    if (d >= K * 128) return;
    int j = d & 7;
    int l = (d >> 3) & 63;
    int t = d >> 9;
    int nt = t & 7;
    int kt = t >> 3;
    int k = kt * 32 + ((l >> 4) << 3) + j;
    int n = (nt << 4) + (l & 15);
    dst[d] = f2bf(src[k * 128 + n]);
}

// ---------------- encoder ----------------
__global__ void encoder_kernel(const float* __restrict__ x, const float* __restrict__ enc_w,
                               const float* __restrict__ enc_b, unsigned short* __restrict__ h) {
    __shared__ float wts[NODE_IN * HID];
    __shared__ float bts[HID];
    __shared__ float xs[64][NODE_IN];
    int t = threadIdx.x;
    int n0 = blockIdx.x * 64;
    for (int i = t; i < NODE_IN * HID; i += 256) wts[i] = enc_w[i];
    if (t < HID) bts[t] = enc_b[t];
    for (int i = t; i < 64 * NODE_IN; i += 256) {
        int nl = i >> 4, ii = i & 15;
        int n = n0 + nl;
        xs[nl][ii] = (n < N_NODES) ? x[n * NODE_IN + ii] : 0.f;
    }
    __syncthreads();
    for (int o = t; o < 64 * HID; o += 256) {
        int nl = o >> 7, c = o & 127;
        int n = n0 + nl;
        if (n >= N_NODES) continue;
        float acc = bts[c];
        #pragma unroll
        for (int i = 0; i < NODE_IN; i++) acc += xs[nl][i] * wts[i * HID + c];
        h[n * HID + c] = f2bf(acc);
    }
}

// ---------------- edge MLP + segmented scatter-reduce (sorted edges) ----------------
__global__ __launch_bounds__(256, 3) void edge_kernel(
    const unsigned short* __restrict__ h,
    const int* __restrict__ rows_sorted, const int* __restrict__ cols_sorted,
    const unsigned short* __restrict__ w1s, const float* __restrict__ b1,
    const unsigned short* __restrict__ w2s, const float* __restrict__ b2,
    float* __restrict__ agg)
{
    // region A: in_s (ushort [64][264], 528B/row) reused as msg_s (float [64][132], 528B/row)
    __shared__ char smemA[64 * 528];
    __shared__ unsigned short hid_s[64][136];
    __shared__ int row_s[64], col_s[64];
    unsigned short (*in_s)[264] = (unsigned short (*)[264])smemA;
    float (*msg_s)[132] = (float (*)[132])smemA;

    int t = threadIdx.x;
    int wave = t >> 6, l = t & 63, q = l >> 4, l16 = l & 15;
    int e0 = blockIdx.x * 64;

    if (t < 64) row_s[t] = rows_sorted[e0 + t];
    else if (t < 128) col_s[t - 64] = cols_sorted[e0 + t - 64];
    __syncthreads();

    // Gather 64 edges x (src row | dst row), 16B per lane-chunk
    #pragma unroll
    for (int it = 0; it < 8; it++) {
        int g = it * 256 + t;
        int el = g >> 5, sub = g & 31, half = sub >> 4, li = sub & 15;
        int node = half ? col_s[el] : row_s[el];
        short8 v = *(const short8*)(h + node * HID + li * 8);
        *(short8*)&in_s[el][half * HID + li * 8] = v;
    }
    __syncthreads();

    // GEMM1: [16 edges/wave x 256] x [256 x 128] -> ReLU -> hid_s
    f32x4 acc[8];
    #pragma unroll
    for (int nt = 0; nt < 8; nt++) acc[nt] = (f32x4){0.f, 0.f, 0.f, 0.f};
    #pragma unroll
    for (int kt = 0; kt < 8; kt++) {
        short8 a = *(const short8*)&in_s[wave * 16 + l16][kt * 32 + q * 8];
        #pragma unroll
        for (int nt = 0; nt < 8; nt++) {
            short8 b = *(const short8*)(w1s + ((kt * 8 + nt) * 64 + l) * 8);
            acc[nt] = __builtin_amdgcn_mfma_f32_16x16x32_bf16(a, b, acc[nt], 0, 0, 0);
        }
    }
    #pragma unroll
    for (int nt = 0; nt < 8; nt++) {
        float bv = b1[nt * 16 + l16];
        #pragma unroll
        for (int r = 0; r < 4; r++) {
            float v = acc[nt][r] + bv;
            v = v > 0.f ? v : 0.f;
            hid_s[wave * 16 + q * 4 + r][nt * 16 + l16] = f2bf(v);
        }
    }
    __syncthreads();   // all GEMM1 in_s reads done; region A free for msg

    // GEMM2: [16 x 128] x [128 x 128] + bias -> msg_s (fp32)
    f32x4 acc2[8];
    #pragma unroll
    for (int nt = 0; nt < 8; nt++) acc2[nt] = (f32x4){0.f, 0.f, 0.f, 0.f};
    #pragma unroll
    for (int kt = 0; kt < 4; kt++) {
        short8 a = *(const short8*)&hid_s[wave * 16 + l16][kt * 32 + q * 8];
        #pragma unroll
        for (int nt = 0; nt < 8; nt++) {
            short8 b = *(const short8*)(w2s + ((kt * 8 + nt) * 64 + l) * 8);
            acc2[nt] = __builtin_amdgcn_mfma_f32_16x16x32_bf16(a, b, acc2[nt], 0, 0, 0);
        }
    }
    #pragma unroll
    for (int nt = 0; nt < 8; nt++) {
        float bv = b2[nt * 16 + l16];
        #pragma unroll
        for (int r = 0; r < 4; r++) {
            msg_s[wave * 16 + q * 4 + r][nt * 16 + l16] = acc2[nt][r] + bv;
        }
    }
    __syncthreads();

    // Segmented reduction over sorted dests: one coalesced atomic per run per column.
    // 256 threads: col = t&127, half = t>>7 owns rows [half*32, half*32+32)
    {
        int c = t & 127;
        int h2 = t >> 7;
        int r0 = h2 * 32;
        float accv = 0.f;
        int cur = col_s[r0];
        #pragma unroll 4
        for (int r = r0; r < r0 + 32; r++) {
            accv += msg_s[r][c];
            int nxt = (r == r0 + 31) ? -1 : col_s[r + 1];
            if (nxt != cur) {
                unsafeAtomicAdd(&agg[cur * HID + c], accv);
                accv = 0.f;
                cur = nxt;
            }
        }
    }
}

// ---------------- node MLP with residual ----------------
__global__ __launch_bounds__(256, 3) void node_kernel(
    unsigned short* __restrict__ h, const float* __restrict__ agg,
    const unsigned short* __restrict__ w1s, const float* __restrict__ b1,
    const unsigned short* __restrict__ w2s, const float* __restrict__ b2)
{
    __shared__ unsigned short in_s[64][264];
    __shared__ unsigned short hid_s[64][136];
    int t = threadIdx.x;
    int wave = t >> 6, l = t & 63, q = l >> 4, l16 = l & 15;
    int n0 = blockIdx.x * 64;

    #pragma unroll
    for (int it = 0; it < 8; it++) {
        int g = it * 256 + t;
        int nl = g >> 5, sub = g & 31, half = sub >> 4, li = sub & 15;
        int n = n0 + nl;
        short8 v = (short8){0, 0, 0, 0, 0, 0, 0, 0};
        if (n < N_NODES) {
            if (half == 0) {
                v = *(const short8*)(h + n * HID + li * 8);
            } else {
                const float* ap = agg + n * HID + li * 8;
                #pragma unroll
                for (int j = 0; j < 8; j++) ((unsigned short*)&v)[j] = f2bf(ap[j]);
            }
        }
        *(short8*)&in_s[nl][half * HID + li * 8] = v;
    }
    __syncthreads();

    f32x4 acc[8];
    #pragma unroll
    for (int nt = 0; nt < 8; nt++) acc[nt] = (f32x4){0.f, 0.f, 0.f, 0.f};
    #pragma unroll
    for (int kt = 0; kt < 8; kt++) {
        short8 a = *(const short8*)&in_s[wave * 16 + l16][kt * 32 + q * 8];
        #pragma unroll
        for (int nt = 0; nt < 8; nt++) {
            short8 b = *(const short8*)(w1s + ((kt * 8 + nt) * 64 + l) * 8);
            acc[nt] = __builtin_amdgcn_mfma_f32_16x16x32_bf16(a, b, acc[nt], 0, 0, 0);
        }
    }
    #pragma unroll
    for (int nt = 0; nt < 8; nt++) {
        float bv = b1[nt * 16 + l16];
        #pragma unroll
        for (int r = 0; r < 4; r++) {
            float v = acc[nt][r] + bv;
            v = v > 0.f ? v : 0.f;
            hid_s[wave * 16 + q * 4 + r][nt * 16 + l16] = f2bf(v);
        }
    }
    __syncthreads();

    f32x4 acc2[8];
    #pragma unroll
    for (int nt = 0; nt < 8; nt++) acc2[nt] = (f32x4){0.f, 0.f, 0.f, 0.f};
    #pragma unroll
    for (int kt = 0; kt < 4; kt++) {
        short8 a = *(const short8*)&hid_s[wave * 16 + l16][kt * 32 + q * 8];
        #pragma unroll
        for (int nt = 0; nt < 8; nt++) {
            short8 b = *(const short8*)(w2s + ((kt * 8 + nt) * 64 + l) * 8);
            acc2[nt] = __builtin_amdgcn_mfma_f32_16x16x32_bf16(a, b, acc2[nt], 0, 0, 0);
        }
    }
    #pragma unroll
    for (int nt = 0; nt < 8; nt++) {
        float bv = b2[nt * 16 + l16];
        #pragma unroll
        for (int r = 0; r < 4; r++) {
            float v = acc2[nt][r] + bv;
            int m2 = wave * 16 + q * 4 + r;
            int n = n0 + m2;
            if (n < N_NODES) {
                int c = nt * 16 + l16;
                float hv = bf2f(in_s[m2][c]);   // old h (half 0)
                h[n * HID + c] = f2bf(hv + v);  // residual
            }
        }
    }
}

// ---------------- decoder ----------------
__global__ void decoder_kernel(const unsigned short* __restrict__ h, const float* __restrict__ dec_w,
                               const float* __restrict__ dec_b, float* __restrict__ out) {
    __shared__ float dw[HID * NODE_OUT];
    __shared__ float db[NODE_OUT];
    int t = threadIdx.x;
    for (int i = t; i < HID * NODE_OUT; i += 256) dw[i] = dec_w[i];
    if (t < NODE_OUT) db[t] = dec_b[t];
    __syncthreads();
    int n = blockIdx.x * 256 + t;
    if (n >= N_NODES) return;
    float a0 = db[0], a1 = db[1], a2 = db[2];
    #pragma unroll 4
    for (int k8 = 0; k8 < 16; k8++) {
        short8 hv = *(const short8*)(h + n * HID + k8 * 8);
        #pragma unroll
        for (int j = 0; j < 8; j++) {
            float f = bf2f(((unsigned short*)&hv)[j]);
            int k = k8 * 8 + j;
            a0 += f * dw[k * 3 + 0];
            a1 += f * dw[k * 3 + 1];
            a2 += f * dw[k * 3 + 2];
        }
    }
    out[n * 3 + 0] = a0;
    out[n * 3 + 1] = a1;
    out[n * 3 + 2] = a2;
}

extern "C" void kernel_launch(void* const* d_in, const int* in_sizes, int n_in,
                              void* d_out, int out_size, void* d_ws, size_t ws_size,
                              hipStream_t stream) {
    const float* x       = (const float*)d_in[0];
    const int*   ei      = (const int*)d_in[1];
    const float* enc_w   = (const float*)d_in[2];
    const float* enc_b   = (const float*)d_in[3];
    const float* dec_w   = (const float*)d_in[4];
    const float* dec_b   = (const float*)d_in[5];
    const float* edge_w1 = (const float*)d_in[6];
    const float* edge_b1 = (const float*)d_in[7];
    const float* edge_w2 = (const float*)d_in[8];
    const float* edge_b2 = (const float*)d_in[9];
    const float* node_w1 = (const float*)d_in[10];
    const float* node_b1 = (const float*)d_in[11];
    const float* node_w2 = (const float*)d_in[12];
    const float* node_b2 = (const float*)d_in[13];

    char* ws = (char*)d_ws;
    unsigned short* h    = (unsigned short*)ws;                    // 12.8 MB
    float*          agg  = (float*)(ws + 12800000);                // 25.6 MB
    unsigned short* swz  = (unsigned short*)(ws + 38400000);       // 589,824 B
    int* cnt             = (int*)(ws + 38989824);                  // 200,000 B
    int* ex              = (int*)(ws + 39189824);                  // 200,000 B
    int* bsums           = (int*)(ws + 39389824);                  // 1,024 B
    int* cursor          = (int*)(ws + 39390848);                  // 200,000 B
    int* rows_sorted     = (int*)(ws + 39590848);                  // 3.2 MB
    int* cols_sorted     = (int*)(ws + 42790848);                  // 3.2 MB -> end 45,990,848

    const int* rowp = ei;            // edge_index[0] = source
    const int* colp = ei + N_EDGES;  // edge_index[1] = destination

    // ---- one-time per call: counting sort of edges by destination ----
    hipMemsetAsync(cnt, 0, (size_t)N_NODES * 4, stream);
    hist_kernel<<<3125, 256, 0, stream>>>(colp, cnt);
    scan1_kernel<<<196, 256, 0, stream>>>(cnt, ex, bsums);
    scan2_kernel<<<1, 256, 0, stream>>>(bsums, 196);
    scan3_kernel<<<196, 256, 0, stream>>>(ex, bsums, cursor);
    scatter_kernel<<<3125, 256, 0, stream>>>(rowp, colp, cursor, rows_sorted, cols_sorted);

    // ---- weight pre-swizzle ----
    for (int L = 0; L < 3; L++) {
        unsigned short* base = swz + (size_t)L * 98304;
        swizzle_w<<<128, 256, 0, stream>>>(edge_w1 + (size_t)L * 256 * 128, base,         256);
        swizzle_w<<<64,  256, 0, stream>>>(edge_w2 + (size_t)L * 128 * 128, base + 32768, 128);
        swizzle_w<<<128, 256, 0, stream>>>(node_w1 + (size_t)L * 256 * 128, base + 49152, 256);
        swizzle_w<<<64,  256, 0, stream>>>(node_w2 + (size_t)L * 128 * 128, base + 81920, 128);
    }

    encoder_kernel<<<782, 256, 0, stream>>>(x, enc_w, enc_b, h);

    for (int L = 0; L < 3; L++) {
        unsigned short* base = swz + (size_t)L * 98304;
        hipMemsetAsync(agg, 0, (size_t)N_NODES * HID * 4, stream);
        edge_kernel<<<12500, 256, 0, stream>>>(h, rows_sorted, cols_sorted,
                                               base,         edge_b1 + (size_t)L * HID,
                                               base + 32768, edge_b2 + (size_t)L * HID, agg);
        node_kernel<<<782, 256, 0, stream>>>(h, agg,
                                             base + 49152, node_b1 + (size_t)L * HID,
                                             base + 81920, node_b2 + (size_t)L * HID);
    }

    decoder_kernel<<<196, 256, 0, stream>>>(h, dec_w, dec_b, (float*)d_out);
}

// Round 3
// 833.984 us; speedup vs baseline: 1.5521x; 1.1356x over previous
//
#include <hip/hip_runtime.h>
#include <hip/hip_bf16.h>
#include <stdint.h>

#define N_NODES 50000
#define N_EDGES 800000
#define HID 128
#define NODE_IN 16
#define NODE_OUT 3

typedef __attribute__((ext_vector_type(8))) short short8;
typedef __attribute__((ext_vector_type(4))) float f32x4;

__device__ __forceinline__ unsigned short f2bf(float f) {
    union { float f; unsigned int u; } v; v.f = f;
    unsigned int u = v.u;
    u += 0x7fff + ((u >> 16) & 1);   // round-to-nearest-even
    return (unsigned short)(u >> 16);
}
__device__ __forceinline__ float bf2f(unsigned short s) {
    union { unsigned int u; float f; } v; v.u = ((unsigned int)s) << 16;
    return v.f;
}

// ---------------- counting sort of edges by destination ----------------

__global__ void hist_kernel(const int* __restrict__ colp, int* __restrict__ cnt) {
    int e = blockIdx.x * 256 + threadIdx.x;
    if (e < N_EDGES) atomicAdd(&cnt[colp[e]], 1);
}

__global__ void scan1_kernel(const int* __restrict__ cnt, int* __restrict__ ex,
                             int* __restrict__ bsums) {
    __shared__ int s[256];
    int t = threadIdx.x, i = blockIdx.x * 256 + t;
    int v = (i < N_NODES) ? cnt[i] : 0;
    s[t] = v;
    __syncthreads();
    for (int off = 1; off < 256; off <<= 1) {
        int u = (t >= off) ? s[t - off] : 0;
        __syncthreads();
        s[t] += u;
        __syncthreads();
    }
    if (i < N_NODES) ex[i] = s[t] - v;
    if (t == 255) bsums[blockIdx.x] = s[255];
}

__global__ void scan2_kernel(int* bsums, int nblk) {
    __shared__ int s[256];
    int t = threadIdx.x;
    int v = (t < nblk) ? bsums[t] : 0;
    s[t] = v;
    __syncthreads();
    for (int off = 1; off < 256; off <<= 1) {
        int u = (t >= off) ? s[t - off] : 0;
        __syncthreads();
        s[t] += u;
        __syncthreads();
    }
    if (t < nblk) bsums[t] = s[t] - v;
}

__global__ void scan3_kernel(const int* __restrict__ ex, const int* __restrict__ bsums,
                             int* __restrict__ cursor) {
    int i = blockIdx.x * 256 + threadIdx.x;
    if (i < N_NODES) cursor[i] = ex[i] + bsums[i >> 8];
}

__global__ void scatter_kernel(const int* __restrict__ rowp, const int* __restrict__ colp,
                               int* __restrict__ cursor,
                               int* __restrict__ rows_sorted, int* __restrict__ cols_sorted) {
    int e = blockIdx.x * 256 + threadIdx.x;
    if (e >= N_EDGES) return;
    int r = rowp[e], c = colp[e];
    int pos = atomicAdd(&cursor[c], 1);
    rows_sorted[pos] = r;
    cols_sorted[pos] = c;
}

// ---------------- weight pre-swizzle into MFMA B-fragment order ----------------
// dst[((kt*8+nt)*64 + lane)*8 + j] = W[kt*32 + (lane>>4)*8 + j][nt*16 + (lane&15)]
__global__ void swizzle_w(const float* __restrict__ src, unsigned short* __restrict__ dst, int K) {
    int d = blockIdx.x * 256 + threadIdx.x;
    if (d >= K * 128) return;
    int j = d & 7;
    int l = (d >> 3) & 63;
    int t = d >> 9;
    int nt = t & 7;
    int kt = t >> 3;
    int k = kt * 32 + ((l >> 4) << 3) + j;
    int n = (nt << 4) + (l & 15);
    dst[d] = f2bf(src[k * 128 + n]);
}

// ---------------- encoder ----------------
__global__ void encoder_kernel(const float* __restrict__ x, const float* __restrict__ enc_w,
                               const float* __restrict__ enc_b, unsigned short* __restrict__ h) {
    __shared__ float wts[NODE_IN * HID];
    __shared__ float bts[HID];
    __shared__ float xs[64][NODE_IN];
    int t = threadIdx.x;
    int n0 = blockIdx.x * 64;
    for (int i = t; i < NODE_IN * HID; i += 256) wts[i] = enc_w[i];
    if (t < HID) bts[t] = enc_b[t];
    for (int i = t; i < 64 * NODE_IN; i += 256) {
        int nl = i >> 4, ii = i & 15;
        int n = n0 + nl;
        xs[nl][ii] = (n < N_NODES) ? x[n * NODE_IN + ii] : 0.f;
    }
    __syncthreads();
    for (int o = t; o < 64 * HID; o += 256) {
        int nl = o >> 7, c = o & 127;
        int n = n0 + nl;
        if (n >= N_NODES) continue;
        float acc = bts[c];
        #pragma unroll
        for (int i = 0; i < NODE_IN; i++) acc += xs[nl][i] * wts[i * HID + c];
        h[n * HID + c] = f2bf(acc);
    }
}

// ---------------- edge MLP + segmented scatter-reduce (sorted edges) ----------------
// Work distribution: each wave owns 2 n-tiles (32 cols) x all 64 edges.
// Per kt: 2 b-frag global loads feed 8 MFMAs (4x b reuse) -> 4x less weight L2 traffic.
__global__ __launch_bounds__(256, 3) void edge_kernel(
    const unsigned short* __restrict__ h,
    const int* __restrict__ rows_sorted, const int* __restrict__ cols_sorted,
    const unsigned short* __restrict__ w1s, const float* __restrict__ b1,
    const unsigned short* __restrict__ w2s, const float* __restrict__ b2,
    float* __restrict__ agg)
{
    __shared__ char smemA[64 * 528];           // in_s ushort[64][264] aliased by msg_s float[64][132]
    __shared__ unsigned short hid_s[64][136];
    __shared__ int row_s[64], col_s[64];
    unsigned short (*in_s)[264] = (unsigned short (*)[264])smemA;
    float (*msg_s)[132] = (float (*)[132])smemA;

    int t = threadIdx.x;
    int wave = t >> 6, l = t & 63, q = l >> 4, l16 = l & 15;
    int nt0 = wave * 2;                        // this wave's n-tiles
    int e0 = blockIdx.x * 64;

    if (t < 64) row_s[t] = rows_sorted[e0 + t];
    else if (t < 128) col_s[t - 64] = cols_sorted[e0 + t - 64];
    __syncthreads();

    // Gather 64 edges x (src row | dst row), 16B per lane-chunk
    #pragma unroll
    for (int it = 0; it < 8; it++) {
        int g = it * 256 + t;
        int el = g >> 5, sub = g & 31, half = sub >> 4, li = sub & 15;
        int node = half ? col_s[el] : row_s[el];
        short8 v = *(const short8*)(h + node * HID + li * 8);
        *(short8*)&in_s[el][half * HID + li * 8] = v;
    }
    __syncthreads();

    // GEMM1: all 64 edges x wave's 32 cols, K=256
    f32x4 acc[4][2];
    #pragma unroll
    for (int g = 0; g < 4; g++)
        #pragma unroll
        for (int j = 0; j < 2; j++) acc[g][j] = (f32x4){0.f, 0.f, 0.f, 0.f};
    #pragma unroll
    for (int kt = 0; kt < 8; kt++) {
        short8 b0 = *(const short8*)(w1s + ((kt * 8 + nt0)     * 64 + l) * 8);
        short8 b1v = *(const short8*)(w1s + ((kt * 8 + nt0 + 1) * 64 + l) * 8);
        #pragma unroll
        for (int g = 0; g < 4; g++) {
            short8 a = *(const short8*)&in_s[g * 16 + l16][kt * 32 + q * 8];
            acc[g][0] = __builtin_amdgcn_mfma_f32_16x16x32_bf16(a, b0, acc[g][0], 0, 0, 0);
            acc[g][1] = __builtin_amdgcn_mfma_f32_16x16x32_bf16(a, b1v, acc[g][1], 0, 0, 0);
        }
    }
    #pragma unroll
    for (int j = 0; j < 2; j++) {
        float bv = b1[(nt0 + j) * 16 + l16];
        #pragma unroll
        for (int g = 0; g < 4; g++)
            #pragma unroll
            for (int r = 0; r < 4; r++) {
                float v = acc[g][j][r] + bv;
                v = v > 0.f ? v : 0.f;
                hid_s[g * 16 + q * 4 + r][(nt0 + j) * 16 + l16] = f2bf(v);
            }
    }
    __syncthreads();   // in_s reads done; hid_s complete

    // GEMM2: K=128 -> msg_s (fp32, aliases in_s)
    f32x4 acc2[4][2];
    #pragma unroll
    for (int g = 0; g < 4; g++)
        #pragma unroll
        for (int j = 0; j < 2; j++) acc2[g][j] = (f32x4){0.f, 0.f, 0.f, 0.f};
    #pragma unroll
    for (int kt = 0; kt < 4; kt++) {
        short8 b0 = *(const short8*)(w2s + ((kt * 8 + nt0)     * 64 + l) * 8);
        short8 b1v = *(const short8*)(w2s + ((kt * 8 + nt0 + 1) * 64 + l) * 8);
        #pragma unroll
        for (int g = 0; g < 4; g++) {
            short8 a = *(const short8*)&hid_s[g * 16 + l16][kt * 32 + q * 8];
            acc2[g][0] = __builtin_amdgcn_mfma_f32_16x16x32_bf16(a, b0, acc2[g][0], 0, 0, 0);
            acc2[g][1] = __builtin_amdgcn_mfma_f32_16x16x32_bf16(a, b1v, acc2[g][1], 0, 0, 0);
        }
    }
    #pragma unroll
    for (int j = 0; j < 2; j++) {
        float bv = b2[(nt0 + j) * 16 + l16];
        #pragma unroll
        for (int g = 0; g < 4; g++)
            #pragma unroll
            for (int r = 0; r < 4; r++) {
                msg_s[g * 16 + q * 4 + r][(nt0 + j) * 16 + l16] = acc2[g][j][r] + bv;
            }
    }
    __syncthreads();

    // Segmented reduction over sorted dests: one coalesced atomic per run per column.
    {
        int c = t & 127;
        int h2 = t >> 7;
        int r0 = h2 * 32;
        float accv = 0.f;
        int cur = col_s[r0];
        #pragma unroll 4
        for (int r = r0; r < r0 + 32; r++) {
            accv += msg_s[r][c];
            int nxt = (r == r0 + 31) ? -1 : col_s[r + 1];
            if (nxt != cur) {
                unsafeAtomicAdd(&agg[cur * HID + c], accv);
                accv = 0.f;
                cur = nxt;
            }
        }
    }
}

// ---------------- node MLP with residual ----------------
__global__ __launch_bounds__(256, 3) void node_kernel(
    unsigned short* __restrict__ h, const float* __restrict__ agg,
    const unsigned short* __restrict__ w1s, const float* __restrict__ b1,
    const unsigned short* __restrict__ w2s, const float* __restrict__ b2)
{
    __shared__ unsigned short in_s[64][264];
    __shared__ unsigned short hid_s[64][136];
    int t = threadIdx.x;
    int wave = t >> 6, l = t & 63, q = l >> 4, l16 = l & 15;
    int nt0 = wave * 2;
    int n0 = blockIdx.x * 64;

    #pragma unroll
    for (int it = 0; it < 8; it++) {
        int g = it * 256 + t;
        int nl = g >> 5, sub = g & 31, half = sub >> 4, li = sub & 15;
        int n = n0 + nl;
        short8 v = (short8){0, 0, 0, 0, 0, 0, 0, 0};
        if (n < N_NODES) {
            if (half == 0) {
                v = *(const short8*)(h + n * HID + li * 8);
            } else {
                const float* ap = agg + n * HID + li * 8;
                #pragma unroll
                for (int j = 0; j < 8; j++) ((unsigned short*)&v)[j] = f2bf(ap[j]);
            }
        }
        *(short8*)&in_s[nl][half * HID + li * 8] = v;
    }
    __syncthreads();

    f32x4 acc[4][2];
    #pragma unroll
    for (int g = 0; g < 4; g++)
        #pragma unroll
        for (int j = 0; j < 2; j++) acc[g][j] = (f32x4){0.f, 0.f, 0.f, 0.f};
    #pragma unroll
    for (int kt = 0; kt < 8; kt++) {
        short8 b0 = *(const short8*)(w1s + ((kt * 8 + nt0)     * 64 + l) * 8);
        short8 b1v = *(const short8*)(w1s + ((kt * 8 + nt0 + 1) * 64 + l) * 8);
        #pragma unroll
        for (int g = 0; g < 4; g++) {
            short8 a = *(const short8*)&in_s[g * 16 + l16][kt * 32 + q * 8];
            acc[g][0] = __builtin_amdgcn_mfma_f32_16x16x32_bf16(a, b0, acc[g][0], 0, 0, 0);
            acc[g][1] = __builtin_amdgcn_mfma_f32_16x16x32_bf16(a, b1v, acc[g][1], 0, 0, 0);
        }
    }
    #pragma unroll
    for (int j = 0; j < 2; j++) {
        float bv = b1[(nt0 + j) * 16 + l16];
        #pragma unroll
        for (int g = 0; g < 4; g++)
            #pragma unroll
            for (int r = 0; r < 4; r++) {
                float v = acc[g][j][r] + bv;
                v = v > 0.f ? v : 0.f;
                hid_s[g * 16 + q * 4 + r][(nt0 + j) * 16 + l16] = f2bf(v);
            }
    }
    __syncthreads();

    f32x4 acc2[4][2];
    #pragma unroll
    for (int g = 0; g < 4; g++)
        #pragma unroll
        for (int j = 0; j < 2; j++) acc2[g][j] = (f32x4){0.f, 0.f, 0.f, 0.f};
    #pragma unroll
    for (int kt = 0; kt < 4; kt++) {
        short8 b0 = *(const short8*)(w2s + ((kt * 8 + nt0)     * 64 + l) * 8);
        short8 b1v = *(const short8*)(w2s + ((kt * 8 + nt0 + 1) * 64 + l) * 8);
        #pragma unroll
        for (int g = 0; g < 4; g++) {
            short8 a = *(const short8*)&hid_s[g * 16 + l16][kt * 32 + q * 8];
            acc2[g][0] = __builtin_amdgcn_mfma_f32_16x16x32_bf16(a, b0, acc2[g][0], 0, 0, 0);
            acc2[g][1] = __builtin_amdgcn_mfma_f32_16x16x32_bf16(a, b1v, acc2[g][1], 0, 0, 0);
        }
    }
    #pragma unroll
    for (int j = 0; j < 2; j++) {
        float bv = b2[(nt0 + j) * 16 + l16];
        #pragma unroll
        for (int g = 0; g < 4; g++)
            #pragma unroll
            for (int r = 0; r < 4; r++) {
                float v = acc2[g][j][r] + bv;
                int m2 = g * 16 + q * 4 + r;
                int n = n0 + m2;
                if (n < N_NODES) {
                    int c = (nt0 + j) * 16 + l16;
                    float hv = bf2f(in_s[m2][c]);   // old h (half 0)
                    h[n * HID + c] = f2bf(hv + v);  // residual
                }
            }
    }
}

// ---------------- decoder ----------------
__global__ void decoder_kernel(const unsigned short* __restrict__ h, const float* __restrict__ dec_w,
                               const float* __restrict__ dec_b, float* __restrict__ out) {
    __shared__ float dw[HID * NODE_OUT];
    __shared__ float db[NODE_OUT];
    int t = threadIdx.x;
    for (int i = t; i < HID * NODE_OUT; i += 256) dw[i] = dec_w[i];
    if (t < NODE_OUT) db[t] = dec_b[t];
    __syncthreads();
    int n = blockIdx.x * 256 + t;
    if (n >= N_NODES) return;
    float a0 = db[0], a1 = db[1], a2 = db[2];
    #pragma unroll 4
    for (int k8 = 0; k8 < 16; k8++) {
        short8 hv = *(const short8*)(h + n * HID + k8 * 8);
        #pragma unroll
        for (int j = 0; j < 8; j++) {
            float f = bf2f(((unsigned short*)&hv)[j]);
            int k = k8 * 8 + j;
            a0 += f * dw[k * 3 + 0];
            a1 += f * dw[k * 3 + 1];
            a2 += f * dw[k * 3 + 2];
        }
    }
    out[n * 3 + 0] = a0;
    out[n * 3 + 1] = a1;
    out[n * 3 + 2] = a2;
}

extern "C" void kernel_launch(void* const* d_in, const int* in_sizes, int n_in,
                              void* d_out, int out_size, void* d_ws, size_t ws_size,
                              hipStream_t stream) {
    const float* x       = (const float*)d_in[0];
    const int*   ei      = (const int*)d_in[1];
    const float* enc_w   = (const float*)d_in[2];
    const float* enc_b   = (const float*)d_in[3];
    const float* dec_w   = (const float*)d_in[4];
    const float* dec_b   = (const float*)d_in[5];
    const float* edge_w1 = (const float*)d_in[6];
    const float* edge_b1 = (const float*)d_in[7];
    const float* edge_w2 = (const float*)d_in[8];
    const float* edge_b2 = (const float*)d_in[9];
    const float* node_w1 = (const float*)d_in[10];
    const float* node_b1 = (const float*)d_in[11];
    const float* node_w2 = (const float*)d_in[12];
    const float* node_b2 = (const float*)d_in[13];

    char* ws = (char*)d_ws;
    unsigned short* h    = (unsigned short*)ws;                    // 12.8 MB
    float*          agg  = (float*)(ws + 12800000);                // 25.6 MB
    unsigned short* swz  = (unsigned short*)(ws + 38400000);       // 589,824 B
    int* cnt             = (int*)(ws + 38989824);
    int* ex              = (int*)(ws + 39189824);
    int* bsums           = (int*)(ws + 39389824);
    int* cursor          = (int*)(ws + 39390848);
    int* rows_sorted     = (int*)(ws + 39590848);                  // 3.2 MB
    int* cols_sorted     = (int*)(ws + 42790848);                  // 3.2 MB

    const int* rowp = ei;            // edge_index[0] = source
    const int* colp = ei + N_EDGES;  // edge_index[1] = destination

    // ---- counting sort of edges by destination ----
    hipMemsetAsync(cnt, 0, (size_t)N_NODES * 4, stream);
    hist_kernel<<<3125, 256, 0, stream>>>(colp, cnt);
    scan1_kernel<<<196, 256, 0, stream>>>(cnt, ex, bsums);
    scan2_kernel<<<1, 256, 0, stream>>>(bsums, 196);
    scan3_kernel<<<196, 256, 0, stream>>>(ex, bsums, cursor);
    scatter_kernel<<<3125, 256, 0, stream>>>(rowp, colp, cursor, rows_sorted, cols_sorted);

    // ---- weight pre-swizzle ----
    for (int L = 0; L < 3; L++) {
        unsigned short* base = swz + (size_t)L * 98304;
        swizzle_w<<<128, 256, 0, stream>>>(edge_w1 + (size_t)L * 256 * 128, base,         256);
        swizzle_w<<<64,  256, 0, stream>>>(edge_w2 + (size_t)L * 128 * 128, base + 32768, 128);
        swizzle_w<<<128, 256, 0, stream>>>(node_w1 + (size_t)L * 256 * 128, base + 49152, 256);
        swizzle_w<<<64,  256, 0, stream>>>(node_w2 + (size_t)L * 128 * 128, base + 81920, 128);
    }

    encoder_kernel<<<782, 256, 0, stream>>>(x, enc_w, enc_b, h);

    for (int L = 0; L < 3; L++) {
        unsigned short* base = swz + (size_t)L * 98304;
        hipMemsetAsync(agg, 0, (size_t)N_NODES * HID * 4, stream);
        edge_kernel<<<12500, 256, 0, stream>>>(h, rows_sorted, cols_sorted,
                                               base,         edge_b1 + (size_t)L * HID,
                                               base + 32768, edge_b2 + (size_t)L * HID, agg);
        node_kernel<<<782, 256, 0, stream>>>(h, agg,
                                             base + 49152, node_b1 + (size_t)L * HID,
                                             base + 81920, node_b2 + (size_t)L * HID);
    }

    decoder_kernel<<<196, 256, 0, stream>>>(h, dec_w, dec_b, (float*)d_out);
}

// Round 4
// 627.756 us; speedup vs baseline: 2.0620x; 1.3285x over previous
//
#include <hip/hip_runtime.h>
#include <hip/hip_bf16.h>
#include <stdint.h>

#define N_NODES 50000
#define N_EDGES 800000
#define HID 128
#define NODE_IN 16
#define NODE_OUT 3
#define EDGE_TILES 12500   // 800000 / 64
#define NODE_TILES 782     // ceil(50000 / 64)

typedef __attribute__((ext_vector_type(8))) short short8;
typedef __attribute__((ext_vector_type(4))) float f32x4;

__device__ __forceinline__ unsigned short f2bf(float f) {
    union { float f; unsigned int u; } v; v.f = f;
    unsigned int u = v.u;
    u += 0x7fff + ((u >> 16) & 1);   // round-to-nearest-even
    return (unsigned short)(u >> 16);
}
__device__ __forceinline__ float bf2f(unsigned short s) {
    union { unsigned int u; float f; } v; v.u = ((unsigned int)s) << 16;
    return v.f;
}

// ---------------- counting sort of edges by destination ----------------

__global__ void hist_kernel(const int* __restrict__ colp, int* __restrict__ cnt) {
    int e = blockIdx.x * 256 + threadIdx.x;
    if (e < N_EDGES) atomicAdd(&cnt[colp[e]], 1);
}

__global__ void scan1_kernel(const int* __restrict__ cnt, int* __restrict__ ex,
                             int* __restrict__ bsums) {
    __shared__ int s[256];
    int t = threadIdx.x, i = blockIdx.x * 256 + t;
    int v = (i < N_NODES) ? cnt[i] : 0;
    s[t] = v;
    __syncthreads();
    for (int off = 1; off < 256; off <<= 1) {
        int u = (t >= off) ? s[t - off] : 0;
        __syncthreads();
        s[t] += u;
        __syncthreads();
    }
    if (i < N_NODES) ex[i] = s[t] - v;
    if (t == 255) bsums[blockIdx.x] = s[255];
}

__global__ void scan2_kernel(int* bsums, int nblk) {
    __shared__ int s[256];
    int t = threadIdx.x;
    int v = (t < nblk) ? bsums[t] : 0;
    s[t] = v;
    __syncthreads();
    for (int off = 1; off < 256; off <<= 1) {
        int u = (t >= off) ? s[t - off] : 0;
        __syncthreads();
        s[t] += u;
        __syncthreads();
    }
    if (t < nblk) bsums[t] = s[t] - v;
}

__global__ void scan3_kernel(const int* __restrict__ ex, const int* __restrict__ bsums,
                             int* __restrict__ cursor) {
    int i = blockIdx.x * 256 + threadIdx.x;
    if (i < N_NODES) cursor[i] = ex[i] + bsums[i >> 8];
}

__global__ void scatter_kernel(const int* __restrict__ rowp, const int* __restrict__ colp,
                               int* __restrict__ cursor,
                               int* __restrict__ rows_sorted, int* __restrict__ cols_sorted) {
    int e = blockIdx.x * 256 + threadIdx.x;
    if (e >= N_EDGES) return;
    int r = rowp[e], c = colp[e];
    int pos = atomicAdd(&cursor[c], 1);
    rows_sorted[pos] = r;
    cols_sorted[pos] = c;
}

// ---------------- weight pre-swizzles into MFMA B-fragment order ----------------
// Standard [K,128] -> 8 n-tiles: dst[((kt*8+nt)*64+lane)*8+j],
// k = kt*32 + (lane>>4)*8 + j, n = nt*16 + (lane&15)
__global__ void swizzle_w(const float* __restrict__ src, unsigned short* __restrict__ dst, int K) {
    int d = blockIdx.x * 256 + threadIdx.x;
    if (d >= K * 128) return;
    int j = d & 7;
    int l = (d >> 3) & 63;
    int t = d >> 9;
    int nt = t & 7;
    int kt = t >> 3;
    int k = kt * 32 + ((l >> 4) << 3) + j;
    int n = (nt << 4) + (l & 15);
    dst[d] = f2bf(src[k * 128 + n]);
}

// edge_w1 [256,128] -> combined [128 x 256] B-frags (16 n-tiles):
// c<128: W1[k][c] (src half), c>=128: W1[128+k][c-128] (dst half)
__global__ void swizzle_w1cat(const float* __restrict__ w1, unsigned short* __restrict__ dst) {
    int d = blockIdx.x * 256 + threadIdx.x;   // 4*16*64*8 = 32768 total
    if (d >= 32768) return;
    int j = d & 7;
    int l = (d >> 3) & 63;
    int t = d >> 9;            // kt*16 + nt
    int nt = t & 15;
    int kt = t >> 4;
    int k = kt * 32 + ((l >> 4) << 3) + j;
    int c = nt * 16 + (l & 15);
    float v = (c < 128) ? w1[k * 128 + c] : w1[(128 + k) * 128 + (c - 128)];
    dst[d] = f2bf(v);
}

// ---------------- encoder ----------------
__global__ void encoder_kernel(const float* __restrict__ x, const float* __restrict__ enc_w,
                               const float* __restrict__ enc_b, unsigned short* __restrict__ h) {
    __shared__ float wts[NODE_IN * HID];
    __shared__ float bts[HID];
    __shared__ float xs[64][NODE_IN];
    int t = threadIdx.x;
    int n0 = blockIdx.x * 64;
    for (int i = t; i < NODE_IN * HID; i += 256) wts[i] = enc_w[i];
    if (t < HID) bts[t] = enc_b[t];
    for (int i = t; i < 64 * NODE_IN; i += 256) {
        int nl = i >> 4, ii = i & 15;
        int n = n0 + nl;
        xs[nl][ii] = (n < N_NODES) ? x[n * NODE_IN + ii] : 0.f;
    }
    __syncthreads();
    for (int o = t; o < 64 * HID; o += 256) {
        int nl = o >> 7, c = o & 127;
        int n = n0 + nl;
        if (n >= N_NODES) continue;
        float acc = bts[c];
        #pragma unroll
        for (int i = 0; i < NODE_IN; i++) acc += xs[nl][i] * wts[i * HID + c];
        h[n * HID + c] = f2bf(acc);
    }
}

// ---------------- S/D precompute: S = h@W1_top, D = h@W1_bot (bf16) ----------------
__global__ __launch_bounds__(256, 2) void sd_kernel(
    const unsigned short* __restrict__ h, const unsigned short* __restrict__ w1c,
    unsigned short* __restrict__ S, unsigned short* __restrict__ D)
{
    int t = threadIdx.x, wave = t >> 6, l = t & 63, q = l >> 4, l16 = l & 15;
    int nt0 = wave * 4;                 // wave covers cols [nt0*16, nt0*16+64) of 256
    int n0 = blockIdx.x * 64;

    short8 wr[4][4];
    #pragma unroll
    for (int kt = 0; kt < 4; kt++)
        #pragma unroll
        for (int i = 0; i < 4; i++)
            wr[kt][i] = *(const short8*)(w1c + ((kt * 16 + nt0 + i) * 64 + l) * 8);

    f32x4 acc[4][4];
    #pragma unroll
    for (int g = 0; g < 4; g++)
        #pragma unroll
        for (int i = 0; i < 4; i++) acc[g][i] = (f32x4){0.f, 0.f, 0.f, 0.f};

    #pragma unroll
    for (int kt = 0; kt < 4; kt++) {
        #pragma unroll
        for (int g = 0; g < 4; g++) {
            int n = n0 + g * 16 + l16;
            if (n > N_NODES - 1) n = N_NODES - 1;   // tail clamp
            short8 a = *(const short8*)(h + n * HID + kt * 32 + q * 8);
            #pragma unroll
            for (int i = 0; i < 4; i++)
                acc[g][i] = __builtin_amdgcn_mfma_f32_16x16x32_bf16(a, wr[kt][i], acc[g][i], 0, 0, 0);
        }
    }
    #pragma unroll
    for (int i = 0; i < 4; i++) {
        int c = (nt0 + i) * 16 + l16;   // [0,256), wave-uniform which half
        #pragma unroll
        for (int g = 0; g < 4; g++)
            #pragma unroll
            for (int r = 0; r < 4; r++) {
                int n = n0 + g * 16 + q * 4 + r;
                if (n < N_NODES) {
                    unsigned short v = f2bf(acc[g][i][r]);
                    if (c < 128) S[n * HID + c] = v;
                    else         D[n * HID + (c - 128)] = v;
                }
            }
    }
}

// ---------------- edge: gather S/D + ReLU -> GEMM2 (reg weights) -> segreduce ----------------
__global__ __launch_bounds__(256, 4) void edge_kernel(
    const unsigned short* __restrict__ S, const unsigned short* __restrict__ D,
    const int* __restrict__ rows_sorted, const int* __restrict__ cols_sorted,
    const float* __restrict__ b1,
    const unsigned short* __restrict__ w2s, const float* __restrict__ b2,
    float* __restrict__ agg)
{
    __shared__ unsigned short hid_s[64][136];   // 17,408 B
    __shared__ unsigned short msg_s[64][136];   // 17,408 B (bf16 messages)
    __shared__ int row_s[64], col_s[64];        // 512 B   -> total 35,328 B -> 4 blocks/CU
    int t = threadIdx.x, wave = t >> 6, l = t & 63, q = l >> 4, l16 = l & 15;
    int nt0 = wave * 2;

    // weights + biases resident in VGPRs across all tiles
    short8 w2r[4][2];
    #pragma unroll
    for (int kt = 0; kt < 4; kt++) {
        w2r[kt][0] = *(const short8*)(w2s + ((kt * 8 + nt0)     * 64 + l) * 8);
        w2r[kt][1] = *(const short8*)(w2s + ((kt * 8 + nt0 + 1) * 64 + l) * 8);
    }
    float b2r0 = b2[nt0 * 16 + l16], b2r1 = b2[(nt0 + 1) * 16 + l16];
    int ch = t & 15;                  // this thread's fixed 8-col chunk in gather
    float b1v[8];
    #pragma unroll
    for (int j = 0; j < 8; j++) b1v[j] = b1[ch * 8 + j];

    for (int tile = blockIdx.x; tile < EDGE_TILES; tile += gridDim.x) {
        int e0 = tile * 64;
        if (t < 64) row_s[t] = rows_sorted[e0 + t];
        else if (t < 128) col_s[t - 64] = cols_sorted[e0 + t - 64];
        __syncthreads();

        // hid = relu(S[row] + D[col] + b1)  (16 lanes cover one row: perfectly coalesced)
        #pragma unroll
        for (int it = 0; it < 4; it++) {
            int el = it * 16 + (t >> 4);
            int r = row_s[el], c = col_s[el];
            short8 sv = *(const short8*)(S + r * HID + ch * 8);
            short8 dv = *(const short8*)(D + c * HID + ch * 8);
            short8 o;
            #pragma unroll
            for (int j = 0; j < 8; j++) {
                float v = bf2f(((unsigned short*)&sv)[j]) + bf2f(((unsigned short*)&dv)[j]) + b1v[j];
                ((unsigned short*)&o)[j] = f2bf(v > 0.f ? v : 0.f);
            }
            *(short8*)&hid_s[el][ch * 8] = o;
        }
        __syncthreads();

        // GEMM2: [64 x 128] x [128 x 32 per wave]
        f32x4 acc2[4][2];
        #pragma unroll
        for (int g = 0; g < 4; g++)
            #pragma unroll
            for (int j = 0; j < 2; j++) acc2[g][j] = (f32x4){0.f, 0.f, 0.f, 0.f};
        #pragma unroll
        for (int kt = 0; kt < 4; kt++) {
            #pragma unroll
            for (int g = 0; g < 4; g++) {
                short8 a = *(const short8*)&hid_s[g * 16 + l16][kt * 32 + q * 8];
                acc2[g][0] = __builtin_amdgcn_mfma_f32_16x16x32_bf16(a, w2r[kt][0], acc2[g][0], 0, 0, 0);
                acc2[g][1] = __builtin_amdgcn_mfma_f32_16x16x32_bf16(a, w2r[kt][1], acc2[g][1], 0, 0, 0);
            }
        }
        #pragma unroll
        for (int j = 0; j < 2; j++) {
            float bv = j ? b2r1 : b2r0;
            #pragma unroll
            for (int g = 0; g < 4; g++)
                #pragma unroll
                for (int r = 0; r < 4; r++)
                    msg_s[g * 16 + q * 4 + r][(nt0 + j) * 16 + l16] = f2bf(acc2[g][j][r] + bv);
        }
        __syncthreads();

        // segmented reduce over sorted dests -> one atomic per run per column
        {
            int c = t & 127;
            int h2 = t >> 7;
            int r0 = h2 * 32;
            float accv = 0.f;
            int cur = col_s[r0];
            #pragma unroll 4
            for (int r = r0; r < r0 + 32; r++) {
                accv += bf2f(msg_s[r][c]);
                int nxt = (r == r0 + 31) ? -1 : col_s[r + 1];
                if (nxt != cur) {
                    unsafeAtomicAdd(&agg[cur * HID + c], accv);
                    accv = 0.f;
                    cur = nxt;
                }
            }
        }
        __syncthreads();   // protect msg_s/col_s before next tile
    }
}

// ---------------- node MLP with residual (reg weights, grid-stride) ----------------
__global__ __launch_bounds__(256, 3) void node_kernel(
    unsigned short* __restrict__ h, const float* __restrict__ agg,
    const unsigned short* __restrict__ w1s, const float* __restrict__ b1,
    const unsigned short* __restrict__ w2s, const float* __restrict__ b2)
{
    __shared__ unsigned short in_s[64][264];
    __shared__ unsigned short hid_s[64][136];
    int t = threadIdx.x, wave = t >> 6, l = t & 63, q = l >> 4, l16 = l & 15;
    int nt0 = wave * 2;

    short8 w1r[8][2], w2r[4][2];
    #pragma unroll
    for (int kt = 0; kt < 8; kt++) {
        w1r[kt][0] = *(const short8*)(w1s + ((kt * 8 + nt0)     * 64 + l) * 8);
        w1r[kt][1] = *(const short8*)(w1s + ((kt * 8 + nt0 + 1) * 64 + l) * 8);
    }
    #pragma unroll
    for (int kt = 0; kt < 4; kt++) {
        w2r[kt][0] = *(const short8*)(w2s + ((kt * 8 + nt0)     * 64 + l) * 8);
        w2r[kt][1] = *(const short8*)(w2s + ((kt * 8 + nt0 + 1) * 64 + l) * 8);
    }
    float b1r0 = b1[nt0 * 16 + l16], b1r1 = b1[(nt0 + 1) * 16 + l16];
    float b2r0 = b2[nt0 * 16 + l16], b2r1 = b2[(nt0 + 1) * 16 + l16];

    for (int tile = blockIdx.x; tile < NODE_TILES; tile += gridDim.x) {
        int n0 = tile * 64;
        #pragma unroll
        for (int it = 0; it < 8; it++) {
            int g = it * 256 + t;
            int nl = g >> 5, sub = g & 31, half = sub >> 4, li = sub & 15;
            int n = n0 + nl;
            short8 v = (short8){0, 0, 0, 0, 0, 0, 0, 0};
            if (n < N_NODES) {
                if (half == 0) {
                    v = *(const short8*)(h + n * HID + li * 8);
                } else {
                    const float* ap = agg + n * HID + li * 8;
                    #pragma unroll
                    for (int j = 0; j < 8; j++) ((unsigned short*)&v)[j] = f2bf(ap[j]);
                }
            }
            *(short8*)&in_s[nl][half * HID + li * 8] = v;
        }
        __syncthreads();

        f32x4 acc[4][2];
        #pragma unroll
        for (int g = 0; g < 4; g++)
            #pragma unroll
            for (int j = 0; j < 2; j++) acc[g][j] = (f32x4){0.f, 0.f, 0.f, 0.f};
        #pragma unroll
        for (int kt = 0; kt < 8; kt++) {
            #pragma unroll
            for (int g = 0; g < 4; g++) {
                short8 a = *(const short8*)&in_s[g * 16 + l16][kt * 32 + q * 8];
                acc[g][0] = __builtin_amdgcn_mfma_f32_16x16x32_bf16(a, w1r[kt][0], acc[g][0], 0, 0, 0);
                acc[g][1] = __builtin_amdgcn_mfma_f32_16x16x32_bf16(a, w1r[kt][1], acc[g][1], 0, 0, 0);
            }
        }
        #pragma unroll
        for (int j = 0; j < 2; j++) {
            float bv = j ? b1r1 : b1r0;
            #pragma unroll
            for (int g = 0; g < 4; g++)
                #pragma unroll
                for (int r = 0; r < 4; r++) {
                    float v = acc[g][j][r] + bv;
                    v = v > 0.f ? v : 0.f;
                    hid_s[g * 16 + q * 4 + r][(nt0 + j) * 16 + l16] = f2bf(v);
                }
        }
        __syncthreads();

        f32x4 acc2[4][2];
        #pragma unroll
        for (int g = 0; g < 4; g++)
            #pragma unroll
            for (int j = 0; j < 2; j++) acc2[g][j] = (f32x4){0.f, 0.f, 0.f, 0.f};
        #pragma unroll
        for (int kt = 0; kt < 4; kt++) {
            #pragma unroll
            for (int g = 0; g < 4; g++) {
                short8 a = *(const short8*)&hid_s[g * 16 + l16][kt * 32 + q * 8];
                acc2[g][0] = __builtin_amdgcn_mfma_f32_16x16x32_bf16(a, w2r[kt][0], acc2[g][0], 0, 0, 0);
                acc2[g][1] = __builtin_amdgcn_mfma_f32_16x16x32_bf16(a, w2r[kt][1], acc2[g][1], 0, 0, 0);
            }
        }
        #pragma unroll
        for (int j = 0; j < 2; j++) {
            float bv = j ? b2r1 : b2r0;
            #pragma unroll
            for (int g = 0; g < 4; g++)
                #pragma unroll
                for (int r = 0; r < 4; r++) {
                    float v = acc2[g][j][r] + bv;
                    int m2 = g * 16 + q * 4 + r;
                    int n = n0 + m2;
                    if (n < N_NODES) {
                        int c = (nt0 + j) * 16 + l16;
                        float hv = bf2f(in_s[m2][c]);   // old h (half 0)
                        h[n * HID + c] = f2bf(hv + v);  // residual
                    }
                }
        }
        __syncthreads();   // protect in_s before next tile's gather
    }
}

// ---------------- decoder ----------------
__global__ void decoder_kernel(const unsigned short* __restrict__ h, const float* __restrict__ dec_w,
                               const float* __restrict__ dec_b, float* __restrict__ out) {
    __shared__ float dw[HID * NODE_OUT];
    __shared__ float db[NODE_OUT];
    int t = threadIdx.x;
    for (int i = t; i < HID * NODE_OUT; i += 256) dw[i] = dec_w[i];
    if (t < NODE_OUT) db[t] = dec_b[t];
    __syncthreads();
    int n = blockIdx.x * 256 + t;
    if (n >= N_NODES) return;
    float a0 = db[0], a1 = db[1], a2 = db[2];
    #pragma unroll 4
    for (int k8 = 0; k8 < 16; k8++) {
        short8 hv = *(const short8*)(h + n * HID + k8 * 8);
        #pragma unroll
        for (int j = 0; j < 8; j++) {
            float f = bf2f(((unsigned short*)&hv)[j]);
            int k = k8 * 8 + j;
            a0 += f * dw[k * 3 + 0];
            a1 += f * dw[k * 3 + 1];
            a2 += f * dw[k * 3 + 2];
        }
    }
    out[n * 3 + 0] = a0;
    out[n * 3 + 1] = a1;
    out[n * 3 + 2] = a2;
}

extern "C" void kernel_launch(void* const* d_in, const int* in_sizes, int n_in,
                              void* d_out, int out_size, void* d_ws, size_t ws_size,
                              hipStream_t stream) {
    const float* x       = (const float*)d_in[0];
    const int*   ei      = (const int*)d_in[1];
    const float* enc_w   = (const float*)d_in[2];
    const float* enc_b   = (const float*)d_in[3];
    const float* dec_w   = (const float*)d_in[4];
    const float* dec_b   = (const float*)d_in[5];
    const float* edge_w1 = (const float*)d_in[6];
    const float* edge_b1 = (const float*)d_in[7];
    const float* edge_w2 = (const float*)d_in[8];
    const float* edge_b2 = (const float*)d_in[9];
    const float* node_w1 = (const float*)d_in[10];
    const float* node_b1 = (const float*)d_in[11];
    const float* node_w2 = (const float*)d_in[12];
    const float* node_b2 = (const float*)d_in[13];

    char* ws = (char*)d_ws;
    unsigned short* h    = (unsigned short*)ws;                    // 12.8 MB
    float*          agg  = (float*)(ws + 12800000);                // 25.6 MB
    unsigned short* swz  = (unsigned short*)(ws + 38400000);       // 589,824 B
    int* cnt             = (int*)(ws + 38989824);
    int* ex              = (int*)(ws + 39189824);
    int* bsums           = (int*)(ws + 39389824);
    int* cursor          = (int*)(ws + 39390848);
    int* rows_sorted     = (int*)(ws + 39590848);                  // 3.2 MB
    int* cols_sorted     = (int*)(ws + 42790848);                  // 3.2 MB
    unsigned short* Sbuf = (unsigned short*)(ws + 45990848);       // 12.8 MB
    unsigned short* Dbuf = (unsigned short*)(ws + 58790848);       // 12.8 MB -> end 71.6 MB

    const int* rowp = ei;            // edge_index[0] = source
    const int* colp = ei + N_EDGES;  // edge_index[1] = destination

    // ---- counting sort of edges by destination ----
    hipMemsetAsync(cnt, 0, (size_t)N_NODES * 4, stream);
    hist_kernel<<<3125, 256, 0, stream>>>(colp, cnt);
    scan1_kernel<<<196, 256, 0, stream>>>(cnt, ex, bsums);
    scan2_kernel<<<1, 256, 0, stream>>>(bsums, 196);
    scan3_kernel<<<196, 256, 0, stream>>>(ex, bsums, cursor);
    scatter_kernel<<<3125, 256, 0, stream>>>(rowp, colp, cursor, rows_sorted, cols_sorted);

    // ---- weight pre-swizzle ----
    // layout per layer: +0: edge w1cat (32768), +32768: edge w2 (16384),
    //                   +49152: node w1 (32768), +81920: node w2 (16384)
    for (int L = 0; L < 3; L++) {
        unsigned short* base = swz + (size_t)L * 98304;
        swizzle_w1cat<<<128, 256, 0, stream>>>(edge_w1 + (size_t)L * 256 * 128, base);
        swizzle_w<<<64,  256, 0, stream>>>(edge_w2 + (size_t)L * 128 * 128, base + 32768, 128);
        swizzle_w<<<128, 256, 0, stream>>>(node_w1 + (size_t)L * 256 * 128, base + 49152, 256);
        swizzle_w<<<64,  256, 0, stream>>>(node_w2 + (size_t)L * 128 * 128, base + 81920, 128);
    }

    encoder_kernel<<<782, 256, 0, stream>>>(x, enc_w, enc_b, h);

    for (int L = 0; L < 3; L++) {
        unsigned short* base = swz + (size_t)L * 98304;
        sd_kernel<<<782, 256, 0, stream>>>(h, base, Sbuf, Dbuf);
        hipMemsetAsync(agg, 0, (size_t)N_NODES * HID * 4, stream);
        edge_kernel<<<2048, 256, 0, stream>>>(Sbuf, Dbuf, rows_sorted, cols_sorted,
                                              edge_b1 + (size_t)L * HID,
                                              base + 32768, edge_b2 + (size_t)L * HID, agg);
        node_kernel<<<768, 256, 0, stream>>>(h, agg,
                                             base + 49152, node_b1 + (size_t)L * HID,
                                             base + 81920, node_b2 + (size_t)L * HID);
    }

    decoder_kernel<<<196, 256, 0, stream>>>(h, dec_w, dec_b, (float*)d_out);
}

// Round 5
// 531.532 us; speedup vs baseline: 2.4353x; 1.1810x over previous
//
#include <hip/hip_runtime.h>
#include <hip/hip_bf16.h>
#include <stdint.h>

#define N_NODES 50000
#define N_EDGES 800000
#define HID 128
#define NODE_IN 16
#define NODE_OUT 3
#define EDGE_TILES 12500   // 800000 / 64
#define NODE_TILES 782     // ceil(50000 / 64)

typedef __attribute__((ext_vector_type(8))) short short8;
typedef __attribute__((ext_vector_type(4))) float f32x4;

__device__ __forceinline__ unsigned short f2bf(float f) {
    union { float f; unsigned int u; } v; v.f = f;
    unsigned int u = v.u;
    u += 0x7fff + ((u >> 16) & 1);   // round-to-nearest-even
    return (unsigned short)(u >> 16);
}
__device__ __forceinline__ float bf2f(unsigned short s) {
    union { unsigned int u; float f; } v; v.u = ((unsigned int)s) << 16;
    return v.f;
}
__device__ __forceinline__ float bfu_lo(unsigned int u) {
    union { unsigned int u; float f; } v; v.u = u << 16; return v.f;
}
__device__ __forceinline__ float bfu_hi(unsigned int u) {
    union { unsigned int u; float f; } v; v.u = u & 0xffff0000u; return v.f;
}

// ---------------- counting sort of edges by destination ----------------

__global__ void hist_kernel(const int* __restrict__ colp, int* __restrict__ cnt) {
    int e = blockIdx.x * 256 + threadIdx.x;
    if (e < N_EDGES) atomicAdd(&cnt[colp[e]], 1);
}

__global__ void scan1_kernel(const int* __restrict__ cnt, int* __restrict__ ex,
                             int* __restrict__ bsums) {
    __shared__ int s[256];
    int t = threadIdx.x, i = blockIdx.x * 256 + t;
    int v = (i < N_NODES) ? cnt[i] : 0;
    s[t] = v;
    __syncthreads();
    for (int off = 1; off < 256; off <<= 1) {
        int u = (t >= off) ? s[t - off] : 0;
        __syncthreads();
        s[t] += u;
        __syncthreads();
    }
    if (i < N_NODES) ex[i] = s[t] - v;
    if (t == 255) bsums[blockIdx.x] = s[255];
}

__global__ void scan2_kernel(int* bsums, int nblk) {
    __shared__ int s[256];
    int t = threadIdx.x;
    int v = (t < nblk) ? bsums[t] : 0;
    s[t] = v;
    __syncthreads();
    for (int off = 1; off < 256; off <<= 1) {
        int u = (t >= off) ? s[t - off] : 0;
        __syncthreads();
        s[t] += u;
        __syncthreads();
    }
    if (t < nblk) bsums[t] = s[t] - v;
}

__global__ void scan3_kernel(const int* __restrict__ ex, const int* __restrict__ bsums,
                             int* __restrict__ cursor) {
    int i = blockIdx.x * 256 + threadIdx.x;
    if (i < N_NODES) cursor[i] = ex[i] + bsums[i >> 8];
}

__global__ void scatter_kernel(const int* __restrict__ rowp, const int* __restrict__ colp,
                               int* __restrict__ cursor,
                               int* __restrict__ rows_sorted, int* __restrict__ cols_sorted) {
    int e = blockIdx.x * 256 + threadIdx.x;
    if (e >= N_EDGES) return;
    int r = rowp[e], c = colp[e];
    int pos = atomicAdd(&cursor[c], 1);
    rows_sorted[pos] = r;
    cols_sorted[pos] = c;
}

// ---------------- all weight pre-swizzles in ONE dispatch ----------------
// Per-layer layout in swz: +0 edge w1cat (32768), +32768 edge w2 (16384),
//                          +49152 node w1 (32768), +81920 node w2 (16384)
__global__ void swizzle_all(const float* __restrict__ edge_w1, const float* __restrict__ edge_w2,
                            const float* __restrict__ node_w1, const float* __restrict__ node_w2,
                            unsigned short* __restrict__ swz) {
    int d = blockIdx.x * 256 + threadIdx.x;
    if (d >= 3 * 98304) return;
    int L = d / 98304;
    int rem = d - L * 98304;
    unsigned short* base = swz + L * 98304;
    if (rem < 32768) {
        // edge w1 combined [128 x 256] B-frags (16 n-tiles), K=128
        const float* w1 = edge_w1 + (size_t)L * 32768;
        int j = rem & 7, l = (rem >> 3) & 63, tt = rem >> 9;
        int nt = tt & 15, kt = tt >> 4;
        int k = kt * 32 + ((l >> 4) << 3) + j;
        int c = nt * 16 + (l & 15);
        float v = (c < 128) ? w1[k * 128 + c] : w1[(128 + k) * 128 + (c - 128)];
        base[rem] = f2bf(v);
    } else if (rem < 49152) {
        // edge w2, K=128 standard swizzle
        int d2 = rem - 32768;
        const float* src = edge_w2 + (size_t)L * 16384;
        int j = d2 & 7, l = (d2 >> 3) & 63, tt = d2 >> 9;
        int nt = tt & 7, kt = tt >> 3;
        int k = kt * 32 + ((l >> 4) << 3) + j, n = (nt << 4) + (l & 15);
        base[rem] = f2bf(src[k * 128 + n]);
    } else if (rem < 81920) {
        // node w1, K=256 standard swizzle
        int d2 = rem - 49152;
        const float* src = node_w1 + (size_t)L * 32768;
        int j = d2 & 7, l = (d2 >> 3) & 63, tt = d2 >> 9;
        int nt = tt & 7, kt = tt >> 3;
        int k = kt * 32 + ((l >> 4) << 3) + j, n = (nt << 4) + (l & 15);
        base[rem] = f2bf(src[k * 128 + n]);
    } else {
        // node w2, K=128 standard swizzle
        int d2 = rem - 81920;
        const float* src = node_w2 + (size_t)L * 16384;
        int j = d2 & 7, l = (d2 >> 3) & 63, tt = d2 >> 9;
        int nt = tt & 7, kt = tt >> 3;
        int k = kt * 32 + ((l >> 4) << 3) + j, n = (nt << 4) + (l & 15);
        base[rem] = f2bf(src[k * 128 + n]);
    }
}

// ---------------- encoder ----------------
__global__ void encoder_kernel(const float* __restrict__ x, const float* __restrict__ enc_w,
                               const float* __restrict__ enc_b, unsigned short* __restrict__ h) {
    __shared__ float wts[NODE_IN * HID];
    __shared__ float bts[HID];
    __shared__ float xs[64][NODE_IN];
    int t = threadIdx.x;
    int n0 = blockIdx.x * 64;
    for (int i = t; i < NODE_IN * HID; i += 256) wts[i] = enc_w[i];
    if (t < HID) bts[t] = enc_b[t];
    for (int i = t; i < 64 * NODE_IN; i += 256) {
        int nl = i >> 4, ii = i & 15;
        int n = n0 + nl;
        xs[nl][ii] = (n < N_NODES) ? x[n * NODE_IN + ii] : 0.f;
    }
    __syncthreads();
    for (int o = t; o < 64 * HID; o += 256) {
        int nl = o >> 7, c = o & 127;
        int n = n0 + nl;
        if (n >= N_NODES) continue;
        float acc = bts[c];
        #pragma unroll
        for (int i = 0; i < NODE_IN; i++) acc += xs[nl][i] * wts[i * HID + c];
        h[n * HID + c] = f2bf(acc);
    }
}

// ---------------- S/D precompute: S = h@W1_top, D = h@W1_bot (bf16) ----------------
__global__ __launch_bounds__(256, 2) void sd_kernel(
    const unsigned short* __restrict__ h, const unsigned short* __restrict__ w1c,
    unsigned short* __restrict__ S, unsigned short* __restrict__ D)
{
    int t = threadIdx.x, wave = t >> 6, l = t & 63, q = l >> 4, l16 = l & 15;
    int nt0 = wave * 4;                 // wave covers cols [nt0*16, nt0*16+64) of 256
    int n0 = blockIdx.x * 64;

    short8 wr[4][4];
    #pragma unroll
    for (int kt = 0; kt < 4; kt++)
        #pragma unroll
        for (int i = 0; i < 4; i++)
            wr[kt][i] = *(const short8*)(w1c + ((kt * 16 + nt0 + i) * 64 + l) * 8);

    f32x4 acc[4][4];
    #pragma unroll
    for (int g = 0; g < 4; g++)
        #pragma unroll
        for (int i = 0; i < 4; i++) acc[g][i] = (f32x4){0.f, 0.f, 0.f, 0.f};

    #pragma unroll
    for (int kt = 0; kt < 4; kt++) {
        #pragma unroll
        for (int g = 0; g < 4; g++) {
            int n = n0 + g * 16 + l16;
            if (n > N_NODES - 1) n = N_NODES - 1;   // tail clamp
            short8 a = *(const short8*)(h + n * HID + kt * 32 + q * 8);
            #pragma unroll
            for (int i = 0; i < 4; i++)
                acc[g][i] = __builtin_amdgcn_mfma_f32_16x16x32_bf16(a, wr[kt][i], acc[g][i], 0, 0, 0);
        }
    }
    #pragma unroll
    for (int i = 0; i < 4; i++) {
        int c = (nt0 + i) * 16 + l16;   // [0,256), wave-uniform which half
        #pragma unroll
        for (int g = 0; g < 4; g++)
            #pragma unroll
            for (int r = 0; r < 4; r++) {
                int n = n0 + g * 16 + q * 4 + r;
                if (n < N_NODES) {
                    unsigned short v = f2bf(acc[g][i][r]);
                    if (c < 128) S[n * HID + c] = v;
                    else         D[n * HID + (c - 128)] = v;
                }
            }
    }
}

// ---------------- edge: gather + relu + fp32 segreduce (NO MFMA, NO GEMM2) ----------------
// aggH[d] += sum_{e->d} relu(S[row_e] + D[d] + b1);  GEMM2 deferred to node_kernel.
__global__ __launch_bounds__(256, 4) void edge_kernel(
    const unsigned short* __restrict__ S, const unsigned short* __restrict__ D,
    const int* __restrict__ rows_sorted, const int* __restrict__ cols_sorted,
    const float* __restrict__ b1, float* __restrict__ aggH)
{
    __shared__ float hid_s[64][132];     // fp32 relu outputs, 33,792 B
    __shared__ int row_s[64], col_s[64]; // 512 B -> 34.3 KB -> 4 blocks/CU
    int t = threadIdx.x;
    int ch = t & 15;                     // this thread's fixed 8-col chunk

    float b1v[8];
    #pragma unroll
    for (int j = 0; j < 8; j++) b1v[j] = b1[ch * 8 + j];

    for (int tile = blockIdx.x; tile < EDGE_TILES; tile += gridDim.x) {
        int e0 = tile * 64;
        if (t < 64) row_s[t] = rows_sorted[e0 + t];
        else if (t < 128) col_s[t - 64] = cols_sorted[e0 + t - 64];
        __syncthreads();

        // hid = relu(S[row] + D[col] + b1), fp32 straight to LDS (no f2bf)
        #pragma unroll
        for (int it = 0; it < 4; it++) {
            int el = it * 16 + (t >> 4);
            int r = row_s[el], c = col_s[el];
            short8 sv = *(const short8*)(S + r * HID + ch * 8);
            short8 dv = *(const short8*)(D + c * HID + ch * 8);
            float o[8];
            #pragma unroll
            for (int p = 0; p < 4; p++) {
                unsigned int us = ((const unsigned int*)&sv)[p];
                unsigned int ud = ((const unsigned int*)&dv)[p];
                float v0 = bfu_lo(us) + bfu_lo(ud) + b1v[p * 2];
                float v1 = bfu_hi(us) + bfu_hi(ud) + b1v[p * 2 + 1];
                o[p * 2]     = v0 > 0.f ? v0 : 0.f;
                o[p * 2 + 1] = v1 > 0.f ? v1 : 0.f;
            }
            *(f32x4*)&hid_s[el][ch * 8]     = *(f32x4*)&o[0];
            *(f32x4*)&hid_s[el][ch * 8 + 4] = *(f32x4*)&o[4];
        }
        __syncthreads();

        // segmented fp32 reduce over sorted dests -> one atomic per run per column
        {
            int c = t & 127;
            int h2 = t >> 7;
            int r0 = h2 * 32;
            float accv = 0.f;
            int cur = col_s[r0];
            #pragma unroll 4
            for (int r = r0; r < r0 + 32; r++) {
                accv += hid_s[r][c];
                int nxt = (r == r0 + 31) ? -1 : col_s[r + 1];
                if (nxt != cur) {
                    unsafeAtomicAdd(&aggH[cur * HID + c], accv);
                    accv = 0.f;
                    cur = nxt;
                }
            }
        }
        __syncthreads();   // protect hid_s/col_s before next tile
    }
}

// ---------------- node: agg = aggH@W2e + cnt*b2e, then node MLP + residual ----------------
__global__ __launch_bounds__(256, 2) void node_kernel(
    unsigned short* __restrict__ h, const float* __restrict__ aggH,
    const int* __restrict__ cnt,
    const unsigned short* __restrict__ w2e_s, const float* __restrict__ b2e,
    const unsigned short* __restrict__ w1s, const float* __restrict__ b1,
    const unsigned short* __restrict__ w2s, const float* __restrict__ b2)
{
    __shared__ unsigned short in_s[64][264];
    __shared__ unsigned short hid_s[64][136];
    __shared__ int cnt_s[64];
    int t = threadIdx.x, wave = t >> 6, l = t & 63, q = l >> 4, l16 = l & 15;
    int nt0 = wave * 2;

    short8 w2er[4][2], w1r[8][2], w2r[4][2];
    #pragma unroll
    for (int kt = 0; kt < 4; kt++) {
        w2er[kt][0] = *(const short8*)(w2e_s + ((kt * 8 + nt0)     * 64 + l) * 8);
        w2er[kt][1] = *(const short8*)(w2e_s + ((kt * 8 + nt0 + 1) * 64 + l) * 8);
    }
    #pragma unroll
    for (int kt = 0; kt < 8; kt++) {
        w1r[kt][0] = *(const short8*)(w1s + ((kt * 8 + nt0)     * 64 + l) * 8);
        w1r[kt][1] = *(const short8*)(w1s + ((kt * 8 + nt0 + 1) * 64 + l) * 8);
    }
    #pragma unroll
    for (int kt = 0; kt < 4; kt++) {
        w2r[kt][0] = *(const short8*)(w2s + ((kt * 8 + nt0)     * 64 + l) * 8);
        w2r[kt][1] = *(const short8*)(w2s + ((kt * 8 + nt0 + 1) * 64 + l) * 8);
    }
    float b2er0 = b2e[nt0 * 16 + l16], b2er1 = b2e[(nt0 + 1) * 16 + l16];
    float b1r0 = b1[nt0 * 16 + l16],  b1r1 = b1[(nt0 + 1) * 16 + l16];
    float b2r0 = b2[nt0 * 16 + l16],  b2r1 = b2[(nt0 + 1) * 16 + l16];

    for (int tile = blockIdx.x; tile < NODE_TILES; tile += gridDim.x) {
        int n0 = tile * 64;
        // stage: h -> in_s half0, bf16(aggH sums) -> in_s half1, cnt -> cnt_s
        #pragma unroll
        for (int it = 0; it < 8; it++) {
            int g = it * 256 + t;
            int nl = g >> 5, sub = g & 31, half = sub >> 4, li = sub & 15;
            int n = n0 + nl;
            short8 v = (short8){0, 0, 0, 0, 0, 0, 0, 0};
            if (n < N_NODES) {
                if (half == 0) {
                    v = *(const short8*)(h + n * HID + li * 8);
                } else {
                    const float* ap = aggH + n * HID + li * 8;
                    #pragma unroll
                    for (int j = 0; j < 8; j++) ((unsigned short*)&v)[j] = f2bf(ap[j]);
                }
            }
            *(short8*)&in_s[nl][half * HID + li * 8] = v;
        }
        if (t < 64) cnt_s[t] = (n0 + t < N_NODES) ? cnt[n0 + t] : 0;
        __syncthreads();

        // deferred edge GEMM2: agg = aggH_sum @ W2e + cnt*b2e  (A from in_s half1)
        f32x4 acce[4][2];
        #pragma unroll
        for (int g = 0; g < 4; g++)
            #pragma unroll
            for (int j = 0; j < 2; j++) acce[g][j] = (f32x4){0.f, 0.f, 0.f, 0.f};
        #pragma unroll
        for (int kt = 0; kt < 4; kt++) {
            #pragma unroll
            for (int g = 0; g < 4; g++) {
                short8 a = *(const short8*)&in_s[g * 16 + l16][HID + kt * 32 + q * 8];
                acce[g][0] = __builtin_amdgcn_mfma_f32_16x16x32_bf16(a, w2er[kt][0], acce[g][0], 0, 0, 0);
                acce[g][1] = __builtin_amdgcn_mfma_f32_16x16x32_bf16(a, w2er[kt][1], acce[g][1], 0, 0, 0);
            }
        }
        __syncthreads();   // all reads of in_s half1 done before overwrite

        #pragma unroll
        for (int j = 0; j < 2; j++) {
            float bv = j ? b2er1 : b2er0;
            #pragma unroll
            for (int g = 0; g < 4; g++)
                #pragma unroll
                for (int r = 0; r < 4; r++) {
                    int m2 = g * 16 + q * 4 + r;
                    float v = acce[g][j][r] + (float)cnt_s[m2] * bv;
                    in_s[m2][HID + (nt0 + j) * 16 + l16] = f2bf(v);
                }
        }
        __syncthreads();

        // node GEMM1 K=256 -> relu -> hid_s
        f32x4 acc[4][2];
        #pragma unroll
        for (int g = 0; g < 4; g++)
            #pragma unroll
            for (int j = 0; j < 2; j++) acc[g][j] = (f32x4){0.f, 0.f, 0.f, 0.f};
        #pragma unroll
        for (int kt = 0; kt < 8; kt++) {
            #pragma unroll
            for (int g = 0; g < 4; g++) {
                short8 a = *(const short8*)&in_s[g * 16 + l16][kt * 32 + q * 8];
                acc[g][0] = __builtin_amdgcn_mfma_f32_16x16x32_bf16(a, w1r[kt][0], acc[g][0], 0, 0, 0);
                acc[g][1] = __builtin_amdgcn_mfma_f32_16x16x32_bf16(a, w1r[kt][1], acc[g][1], 0, 0, 0);
            }
        }
        #pragma unroll
        for (int j = 0; j < 2; j++) {
            float bv = j ? b1r1 : b1r0;
            #pragma unroll
            for (int g = 0; g < 4; g++)
                #pragma unroll
                for (int r = 0; r < 4; r++) {
                    float v = acc[g][j][r] + bv;
                    v = v > 0.f ? v : 0.f;
                    hid_s[g * 16 + q * 4 + r][(nt0 + j) * 16 + l16] = f2bf(v);
                }
        }
        __syncthreads();

        // node GEMM2 K=128 -> +residual -> h
        f32x4 acc2[4][2];
        #pragma unroll
        for (int g = 0; g < 4; g++)
            #pragma unroll
            for (int j = 0; j < 2; j++) acc2[g][j] = (f32x4){0.f, 0.f, 0.f, 0.f};
        #pragma unroll
        for (int kt = 0; kt < 4; kt++) {
            #pragma unroll
            for (int g = 0; g < 4; g++) {
                short8 a = *(const short8*)&hid_s[g * 16 + l16][kt * 32 + q * 8];
                acc2[g][0] = __builtin_amdgcn_mfma_f32_16x16x32_bf16(a, w2r[kt][0], acc2[g][0], 0, 0, 0);
                acc2[g][1] = __builtin_amdgcn_mfma_f32_16x16x32_bf16(a, w2r[kt][1], acc2[g][1], 0, 0, 0);
            }
        }
        #pragma unroll
        for (int j = 0; j < 2; j++) {
            float bv = j ? b2r1 : b2r0;
            #pragma unroll
            for (int g = 0; g < 4; g++)
                #pragma unroll
                for (int r = 0; r < 4; r++) {
                    float v = acc2[g][j][r] + bv;
                    int m2 = g * 16 + q * 4 + r;
                    int n = n0 + m2;
                    if (n < N_NODES) {
                        int c = (nt0 + j) * 16 + l16;
                        float hv = bf2f(in_s[m2][c]);   // old h (half 0, still intact)
                        h[n * HID + c] = f2bf(hv + v);  // residual
                    }
                }
        }
        __syncthreads();   // protect in_s/hid_s before next tile
    }
}

// ---------------- decoder ----------------
__global__ void decoder_kernel(const unsigned short* __restrict__ h, const float* __restrict__ dec_w,
                               const float* __restrict__ dec_b, float* __restrict__ out) {
    __shared__ float dw[HID * NODE_OUT];
    __shared__ float db[NODE_OUT];
    int t = threadIdx.x;
    for (int i = t; i < HID * NODE_OUT; i += 256) dw[i] = dec_w[i];
    if (t < NODE_OUT) db[t] = dec_b[t];
    __syncthreads();
    int n = blockIdx.x * 256 + t;
    if (n >= N_NODES) return;
    float a0 = db[0], a1 = db[1], a2 = db[2];
    #pragma unroll 4
    for (int k8 = 0; k8 < 16; k8++) {
        short8 hv = *(const short8*)(h + n * HID + k8 * 8);
        #pragma unroll
        for (int j = 0; j < 8; j++) {
            float f = bf2f(((unsigned short*)&hv)[j]);
            int k = k8 * 8 + j;
            a0 += f * dw[k * 3 + 0];
            a1 += f * dw[k * 3 + 1];
            a2 += f * dw[k * 3 + 2];
        }
    }
    out[n * 3 + 0] = a0;
    out[n * 3 + 1] = a1;
    out[n * 3 + 2] = a2;
}

extern "C" void kernel_launch(void* const* d_in, const int* in_sizes, int n_in,
                              void* d_out, int out_size, void* d_ws, size_t ws_size,
                              hipStream_t stream) {
    const float* x       = (const float*)d_in[0];
    const int*   ei      = (const int*)d_in[1];
    const float* enc_w   = (const float*)d_in[2];
    const float* enc_b   = (const float*)d_in[3];
    const float* dec_w   = (const float*)d_in[4];
    const float* dec_b   = (const float*)d_in[5];
    const float* edge_w1 = (const float*)d_in[6];
    const float* edge_b1 = (const float*)d_in[7];
    const float* edge_w2 = (const float*)d_in[8];
    const float* edge_b2 = (const float*)d_in[9];
    const float* node_w1 = (const float*)d_in[10];
    const float* node_b1 = (const float*)d_in[11];
    const float* node_w2 = (const float*)d_in[12];
    const float* node_b2 = (const float*)d_in[13];

    char* ws = (char*)d_ws;
    unsigned short* h    = (unsigned short*)ws;                    // 12.8 MB
    float*          aggH = (float*)(ws + 12800000);                // 25.6 MB
    unsigned short* swz  = (unsigned short*)(ws + 38400000);       // 589,824 B
    int* cnt             = (int*)(ws + 38989824);                  // degrees (kept!)
    int* ex              = (int*)(ws + 39189824);
    int* bsums           = (int*)(ws + 39389824);
    int* cursor          = (int*)(ws + 39390848);
    int* rows_sorted     = (int*)(ws + 39590848);                  // 3.2 MB
    int* cols_sorted     = (int*)(ws + 42790848);                  // 3.2 MB
    unsigned short* Sbuf = (unsigned short*)(ws + 45990848);       // 12.8 MB
    unsigned short* Dbuf = (unsigned short*)(ws + 58790848);       // 12.8 MB -> end 71.6 MB

    const int* rowp = ei;            // edge_index[0] = source
    const int* colp = ei + N_EDGES;  // edge_index[1] = destination

    // ---- counting sort of edges by destination (cnt doubles as degree) ----
    hipMemsetAsync(cnt, 0, (size_t)N_NODES * 4, stream);
    hist_kernel<<<3125, 256, 0, stream>>>(colp, cnt);
    scan1_kernel<<<196, 256, 0, stream>>>(cnt, ex, bsums);
    scan2_kernel<<<1, 256, 0, stream>>>(bsums, 196);
    scan3_kernel<<<196, 256, 0, stream>>>(ex, bsums, cursor);
    scatter_kernel<<<3125, 256, 0, stream>>>(rowp, colp, cursor, rows_sorted, cols_sorted);

    // ---- all weight pre-swizzles in one dispatch ----
    swizzle_all<<<1152, 256, 0, stream>>>(edge_w1, edge_w2, node_w1, node_w2, swz);

    encoder_kernel<<<782, 256, 0, stream>>>(x, enc_w, enc_b, h);

    for (int L = 0; L < 3; L++) {
        unsigned short* base = swz + (size_t)L * 98304;
        sd_kernel<<<782, 256, 0, stream>>>(h, base, Sbuf, Dbuf);
        hipMemsetAsync(aggH, 0, (size_t)N_NODES * HID * 4, stream);
        edge_kernel<<<1024, 256, 0, stream>>>(Sbuf, Dbuf, rows_sorted, cols_sorted,
                                              edge_b1 + (size_t)L * HID, aggH);
        node_kernel<<<512, 256, 0, stream>>>(h, aggH, cnt,
                                             base + 32768, edge_b2 + (size_t)L * HID,
                                             base + 49152, node_b1 + (size_t)L * HID,
                                             base + 81920, node_b2 + (size_t)L * HID);
    }

    decoder_kernel<<<196, 256, 0, stream>>>(h, dec_w, dec_b, (float*)d_out);
}